// Round 9
// baseline (315.467 us; speedup 1.0000x reference)
//
#include <hip/hip_runtime.h>
#include <hip/hip_bf16.h>

// Problem constants
#define S_   3
#define B_   4096
#define DIN_ 1024
#define H1_  512
#define H2_  384
#define H3_  256
#define D_   128
#define K_   512
#define C_   3
#define INV_T 10.0f          // 1/TEMP
#define EPS_  1e-12f
#define EXP10 22026.465794806718f   // exp(1/T), diag(refl) analytically

typedef float f32x4 __attribute__((ext_vector_type(4)));
typedef short bf16x8 __attribute__((ext_vector_type(8)));

__device__ __forceinline__ unsigned short f2bf(float f) {
  unsigned int u = __float_as_uint(f);
  u = (u + 0x7FFF + ((u >> 16) & 1)) >> 16;   // round-to-nearest-even
  return (unsigned short)u;
}

// ---------------- reduction helpers ----------------
__device__ __forceinline__ float waveReduceSum(float v) {
#pragma unroll
  for (int off = 32; off > 0; off >>= 1) v += __shfl_down(v, off, 64);
  return v;
}

__device__ __forceinline__ float waveXorSum(float v) {
#pragma unroll
  for (int off = 32; off > 0; off >>= 1) v += __shfl_xor(v, off, 64);
  return v;
}

__device__ __forceinline__ float blockReduceSum128(float v, float* sbuf) {
  v = waveReduceSum(v);
  if ((threadIdx.x & 63) == 0) sbuf[threadIdx.x >> 6] = v;
  __syncthreads();
  float r = sbuf[0] + sbuf[1];
  __syncthreads();
  return r;
}

// ---------------- fp32 -> bf16 elementwise (n % 1024 == 0) ----------------
__global__ __launch_bounds__(256) void cvt_bf16_kernel(const float* __restrict__ in,
                                                       unsigned short* __restrict__ out,
                                                       int n) {
  int i = (blockIdx.x * 256 + threadIdx.x) * 4;
  if (i < n) {
    float4 v = *(const float4*)(in + i);
    out[i + 0] = f2bf(v.x); out[i + 1] = f2bf(v.y);
    out[i + 2] = f2bf(v.z); out[i + 3] = f2bf(v.w);
  }
}

// ---------------- W[S][K][N] fp32 -> Wt[S][N][K] bf16 ------
__global__ __launch_bounds__(256) void transpose_w_kernel(const float* __restrict__ W,
                                                          unsigned short* __restrict__ Wt,
                                                          int K, int N) {
  const int s = blockIdx.z;
  const int k0 = blockIdx.x * 32, n0 = blockIdx.y * 32;
  const int tx = threadIdx.x, ty = threadIdx.y;
  __shared__ float t[32][33];
  const float* Ws = W + (size_t)s * K * N;
  unsigned short* Wts = Wt + (size_t)s * N * K;
#pragma unroll
  for (int i = 0; i < 4; i++)
    t[ty + 8 * i][tx] = Ws[(size_t)(k0 + ty + 8 * i) * N + n0 + tx];
  __syncthreads();
#pragma unroll
  for (int i = 0; i < 4; i++)
    Wts[(size_t)(n0 + ty + 8 * i) * K + k0 + tx] = f2bf(t[tx][ty + 8 * i]);
}

// ---------------- LDS-staged MFMA GEMM, BK=64, register-pipelined ----------------
// Tile 64(M) x 128(N), BK=64 in two 32-k half-buffers (64B rows, no new bank
// pattern). Block 256 = 4 waves 2x2; wave tile 32x64 -> 16 MFMAs per k-step.
// grid = (N/128, Mtot/64). K % 64 == 0.
__global__ __launch_bounds__(256) void gemm_lds_kernel(
    const unsigned short* __restrict__ A, const unsigned short* __restrict__ Wt,
    const float* __restrict__ bias, void* __restrict__ Y,
    int K, int N, int relu, int out_f32) {
  const int t = threadIdx.x;
  const int lane = t & 63;
  const int w = t >> 6;
  const int ln = lane & 15, q = lane >> 4;
  const int wm = w >> 1, wn = w & 1;
  const int n0 = blockIdx.x * 128;
  const int mblk = blockIdx.y;
  const int s = mblk >> 6;                  // 4096/64 = 64 m-blocks per source
  const int m0 = mblk * 64;

  const unsigned short* Ag = A + (size_t)m0 * K;
  const unsigned short* Bg = Wt + (size_t)s * N * K + (size_t)n0 * K;
  const float* bs = bias + (size_t)s * N;

  __shared__ unsigned short Asm[2 * 64 * 32];    // two 32-k halves, 64B rows
  __shared__ unsigned short Bsm[2 * 128 * 32];

  // chunk c (8 shorts): row = c>>3, k8 = c&7; ksl = k8>>2; col = (k8&3)*8
  // A chunks: c = t, t+256.  B chunks: c = t, t+256, t+512, t+768.
  const int arow0 = t >> 3, ak8 = t & 7;
  const int aL0 = (ak8 >> 2) * 2048 + arow0 * 32 + (ak8 & 3) * 8;
  const int bL0 = (ak8 >> 2) * 4096 + arow0 * 32 + (ak8 & 3) * 8;
  const size_t gA0 = (size_t)arow0 * K + ak8 * 8;

  bf16x8 ra0 = *(const bf16x8*)(Ag + gA0);
  bf16x8 ra1 = *(const bf16x8*)(Ag + gA0 + (size_t)32 * K);
  bf16x8 rb0 = *(const bf16x8*)(Bg + gA0);
  bf16x8 rb1 = *(const bf16x8*)(Bg + gA0 + (size_t)32 * K);
  bf16x8 rb2 = *(const bf16x8*)(Bg + gA0 + (size_t)64 * K);
  bf16x8 rb3 = *(const bf16x8*)(Bg + gA0 + (size_t)96 * K);

  f32x4 acc[2][4];
#pragma unroll
  for (int i = 0; i < 2; i++)
#pragma unroll
    for (int j = 0; j < 4; j++) acc[i][j] = (f32x4){0.f, 0.f, 0.f, 0.f};

  for (int k0 = 0; k0 < K; k0 += 64) {
    *(bf16x8*)&Asm[aL0] = ra0;
    *(bf16x8*)&Asm[aL0 + 1024] = ra1;          // row+32 within same half
    *(bf16x8*)&Bsm[bL0] = rb0;
    *(bf16x8*)&Bsm[bL0 + 1024] = rb1;
    *(bf16x8*)&Bsm[bL0 + 2048] = rb2;
    *(bf16x8*)&Bsm[bL0 + 3072] = rb3;
    __syncthreads();
    if (k0 + 64 < K) {
      const size_t g = gA0 + k0 + 64;
      ra0 = *(const bf16x8*)(Ag + g);
      ra1 = *(const bf16x8*)(Ag + g + (size_t)32 * K);
      rb0 = *(const bf16x8*)(Bg + g);
      rb1 = *(const bf16x8*)(Bg + g + (size_t)32 * K);
      rb2 = *(const bf16x8*)(Bg + g + (size_t)64 * K);
      rb3 = *(const bf16x8*)(Bg + g + (size_t)96 * K);
    }
    bf16x8 af[2][2], bf[4][2];
#pragma unroll
    for (int ti = 0; ti < 2; ti++)
#pragma unroll
      for (int ksl = 0; ksl < 2; ksl++)
        af[ti][ksl] = *(const bf16x8*)&Asm[ksl * 2048 + (wm * 32 + ti * 16 + ln) * 32 + q * 8];
#pragma unroll
    for (int tj = 0; tj < 4; tj++)
#pragma unroll
      for (int ksl = 0; ksl < 2; ksl++)
        bf[tj][ksl] = *(const bf16x8*)&Bsm[ksl * 4096 + (wn * 64 + tj * 16 + ln) * 32 + q * 8];
#pragma unroll
    for (int ksl = 0; ksl < 2; ksl++)
#pragma unroll
      for (int ti = 0; ti < 2; ti++)
#pragma unroll
        for (int tj = 0; tj < 4; tj++)
          acc[ti][tj] = __builtin_amdgcn_mfma_f32_16x16x32_bf16(af[ti][ksl], bf[tj][ksl], acc[ti][tj], 0, 0, 0);
    __syncthreads();
  }

#pragma unroll
  for (int ti = 0; ti < 2; ti++)
#pragma unroll
    for (int tj = 0; tj < 4; tj++) {
      const int cc = n0 + wn * 64 + tj * 16 + ln;
      const float bv = bs[cc];
#pragma unroll
      for (int reg = 0; reg < 4; reg++) {
        const int r = m0 + wm * 32 + ti * 16 + q * 4 + reg;
        float v = acc[ti][tj][reg] + bv;
        if (relu) v = fmaxf(v, 0.0f);
        if (out_f32) ((float*)Y)[(size_t)r * N + cc] = v;
        else ((unsigned short*)Y)[(size_t)r * N + cc] = f2bf(v);
      }
    }
}

// ---------------- attention score, batched: block = 4 b x 3 s rows ----------------
__global__ __launch_bounds__(256) void score_kernel(
    const float* __restrict__ emb, const float* __restrict__ qw1,
    const float* __restrict__ qb1, const float* __restrict__ qw2,
    float* __restrict__ score) {
  const int b0 = blockIdx.x * 4;
  const int t = threadIdx.x;
  const int g = t >> 7, d = t & 127;
  __shared__ float e[12][D_];
  __shared__ float red[4][6];
#pragma unroll
  for (int i = 0; i < 3; i++) {
    int idx = i * 512 + t * 2;
    int r = idx >> 7, dd = idx & 127;
    int s = r >> 2, bi = r & 3;
    *(float2*)&e[r][dd] = *(const float2*)(emb + ((size_t)(s * B_ + b0 + bi)) * D_ + dd);
  }
  __syncthreads();
  float acc[6] = {0.f, 0.f, 0.f, 0.f, 0.f, 0.f};
  for (int i = 0; i < D_; i++) {
    float w = qw1[i * D_ + d];
#pragma unroll
    for (int j = 0; j < 6; j++) acc[j] = fmaf(e[g * 6 + j][i], w, acc[j]);
  }
  const float qb = qb1[d], q2 = qw2[d];
  float val[6];
#pragma unroll
  for (int j = 0; j < 6; j++) val[j] = tanhf(acc[j] + qb) * q2;
  const int wave = t >> 6;
#pragma unroll
  for (int j = 0; j < 6; j++) {
    float v = waveReduceSum(val[j]);
    if ((t & 63) == 0) red[wave][j] = v;
  }
  __syncthreads();
  if (t < 12) {
    int gg = t / 6, j = t % 6;
    int r = gg * 6 + j;
    int s = r >> 2, bi = r & 3;
    score[s * B_ + b0 + bi] = red[2 * gg][j] + red[2 * gg + 1][j];
  }
}

// ---------------- softmax over S + fuse ----------------
__global__ __launch_bounds__(128) void fuse_kernel(
    const float* __restrict__ emb, const float* __restrict__ score,
    float* __restrict__ fused) {
  const int b = blockIdx.x, d = threadIdx.x;
  float s0 = score[0 * B_ + b], s1 = score[1 * B_ + b], s2 = score[2 * B_ + b];
  float mx = fmaxf(s0, fmaxf(s1, s2));
  float e0 = __expf(s0 - mx), e1 = __expf(s1 - mx), e2 = __expf(s2 - mx);
  float inv = 1.0f / (e0 + e1 + e2);
  fused[(long long)b * D_ + d] =
      e0 * inv * emb[(long long)(0 * B_ + b) * D_ + d] +
      e1 * inv * emb[(long long)(1 * B_ + b) * D_ + d] +
      e2 * inv * emb[(long long)(2 * B_ + b) * D_ + d];
}

// ---------------- codebook squared norms ----------------
__global__ __launch_bounds__(64) void cbnorm2_kernel(const float* __restrict__ cb,
                                                     float* __restrict__ cbn2) {
  const int r = blockIdx.x, lane = threadIdx.x;
  const float* row = cb + (long long)r * D_;
  float v0 = row[lane], v1 = row[lane + 64];
  float t = waveReduceSum(v0 * v0 + v1 * v1);
  if (lane == 0) cbn2[r] = t;
}

// ---------------- residual VQ v3: MFMA distance GEMM ----------------
__global__ __launch_bounds__(512) void vq_mfma_kernel(
    const float* __restrict__ fused, const float* __restrict__ cb,
    const unsigned short* __restrict__ cbb, const float* __restrict__ cbn2,
    float* __restrict__ qsum) {
  const int r0 = blockIdx.x * 16;
  const int t = threadIdx.x;
  const int w = t >> 6, lane = t & 63;
  const int ln = lane & 15, q = lane >> 4;
  __shared__ float resv[16][D_];
  __shared__ unsigned short resb[16][D_];
  __shared__ float candd[8][16];
  __shared__ int candk[8][16];
  __shared__ int bestk[16];

  {
    int idx = t * 4;
    int r = idx >> 7, dd = idx & 127;
    float4 v = *(const float4*)(fused + (size_t)(r0 + r) * D_ + dd);
    *(float4*)&resv[r][dd] = v;
    resb[r][dd + 0] = f2bf(v.x); resb[r][dd + 1] = f2bf(v.y);
    resb[r][dd + 2] = f2bf(v.z); resb[r][dd + 3] = f2bf(v.w);
  }
  __syncthreads();

  for (int c = 0; c < C_; c++) {
    bf16x8 a[4];
#pragma unroll
    for (int ks = 0; ks < 4; ks++)
      a[ks] = *(const bf16x8*)&resb[ln][ks * 32 + q * 8];
    f32x4 acc[4];
#pragma unroll
    for (int tt = 0; tt < 4; tt++) acc[tt] = (f32x4){0.f, 0.f, 0.f, 0.f};
#pragma unroll
    for (int tt = 0; tt < 4; tt++) {
      const int n = w * 64 + tt * 16 + ln;
      const unsigned short* bp = cbb + ((size_t)c * K_ + n) * D_;
#pragma unroll
      for (int ks = 0; ks < 4; ks++) {
        bf16x8 b = *(const bf16x8*)(bp + ks * 32 + q * 8);
        acc[tt] = __builtin_amdgcn_mfma_f32_16x16x32_bf16(a[ks], b, acc[tt], 0, 0, 0);
      }
    }
    float bd[4]; int bk[4];
#pragma unroll
    for (int reg = 0; reg < 4; reg++) { bd[reg] = 3.4e38f; bk[reg] = 0x7fffffff; }
#pragma unroll
    for (int tt = 0; tt < 4; tt++) {
      const int col = w * 64 + tt * 16 + ln;
      const float n2 = cbn2[c * K_ + col];
#pragma unroll
      for (int reg = 0; reg < 4; reg++) {
        float dist = n2 - 2.0f * acc[tt][reg];
        if (dist < bd[reg] || (dist == bd[reg] && col < bk[reg])) { bd[reg] = dist; bk[reg] = col; }
      }
    }
#pragma unroll
    for (int reg = 0; reg < 4; reg++) {
#pragma unroll
      for (int off = 8; off > 0; off >>= 1) {
        float d1 = __shfl_down(bd[reg], off, 16);
        int k1 = __shfl_down(bk[reg], off, 16);
        if (d1 < bd[reg] || (d1 == bd[reg] && k1 < bk[reg])) { bd[reg] = d1; bk[reg] = k1; }
      }
      if (ln == 0) { candd[w][q * 4 + reg] = bd[reg]; candk[w][q * 4 + reg] = bk[reg]; }
    }
    __syncthreads();
    if (w == 0) {
      int row = lane >> 2, g = lane & 3;
      float d0 = candd[2 * g][row]; int k0 = candk[2 * g][row];
      float d1 = candd[2 * g + 1][row]; int k1 = candk[2 * g + 1][row];
      if (d1 < d0 || (d1 == d0 && k1 < k0)) { d0 = d1; k0 = k1; }
#pragma unroll
      for (int off = 2; off > 0; off >>= 1) {
        float dn = __shfl_down(d0, off, 4);
        int kn = __shfl_down(k0, off, 4);
        if (dn < d0 || (dn == d0 && kn < k0)) { d0 = dn; k0 = kn; }
      }
      if (g == 0) bestk[row] = k0;
    }
    __syncthreads();
    {
      int idx = t * 4;
      int r = idx >> 7, dd = idx & 127;
      const float4 qv = *(const float4*)(cb + ((size_t)c * K_ + bestk[r]) * D_ + dd);
      float4 rv = *(float4*)&resv[r][dd];
      rv.x -= qv.x; rv.y -= qv.y; rv.z -= qv.z; rv.w -= qv.w;
      *(float4*)&resv[r][dd] = rv;
      resb[r][dd + 0] = f2bf(rv.x); resb[r][dd + 1] = f2bf(rv.y);
      resb[r][dd + 2] = f2bf(rv.z); resb[r][dd + 3] = f2bf(rv.w);
    }
    __syncthreads();
  }

  {
    int idx = t * 4;
    int r = idx >> 7, dd = idx & 127;
    float4 f = *(const float4*)(fused + (size_t)(r0 + r) * D_ + dd);
    float4 rv = *(float4*)&resv[r][dd];
    f.x -= rv.x; f.y -= rv.y; f.z -= rv.z; f.w -= rv.w;
    *(float4*)(qsum + (size_t)(r0 + r) * D_ + dd) = f;
  }
}

// ---------------- normalize rows + bf16 copy (wave-per-row, 4 rows/block) --------
__global__ __launch_bounds__(256) void normalize_kernel(
    const float* __restrict__ qsum, const float* __restrict__ emb,
    float* __restrict__ z, unsigned short* __restrict__ zb) {
  const int g = blockIdx.x * 4 + (threadIdx.x >> 6);
  const int lane = threadIdx.x & 63;
  const float* src = (g < B_) ? (qsum + (size_t)g * D_) : (emb + (size_t)(g - B_) * D_);
  float2 v = *(const float2*)(src + lane * 2);
  float n2 = waveXorSum(v.x * v.x + v.y * v.y);
  float inv = 1.0f / fmaxf(sqrtf(n2), EPS_);
  float zx = v.x * inv, zy = v.y * inv;
  *(float2*)(z + (size_t)g * D_ + lane * 2) = make_float2(zx, zy);
  zb[(size_t)g * D_ + lane * 2 + 0] = f2bf(zx);
  zb[(size_t)g * D_ + lane * 2 + 1] = f2bf(zy);
}

// ---------------- contrastive exp-rowsums v3: occupancy-first ----------------
// grid (8 jc, 32 ib, 4 m) = 1024 blocks (exactly 4 blocks/CU, all resident).
// Block 256 = 4 waves stacked in i (128 i/block); wave tile 32i x 64j,
// jt loop over 8 tiles (512 j/block). A-frags (8 regs) loaded once per wave;
// acc[2][4]=32 regs; exp accumulates in e[2][4]; one epilogue per block.
__global__ __launch_bounds__(256) void contrast_mfma_kernel(
    const unsigned short* __restrict__ zb, float* __restrict__ rsP) {
  const int jc = blockIdx.x, ib = blockIdx.y, m = blockIdx.z;
  const int w = threadIdx.x >> 6, lane = threadIdx.x & 63;
  const int ln = lane & 15, q = lane >> 4;
  const int i0 = ib * 128 + w * 32;
  const unsigned short* Za = zb;
  const unsigned short* Zm = zb + (size_t)m * B_ * D_;

  bf16x8 a[2][4];
#pragma unroll
  for (int si = 0; si < 2; si++)
#pragma unroll
    for (int ks = 0; ks < 4; ks++)
      a[si][ks] = *(const bf16x8*)(Za + (size_t)(i0 + si * 16 + ln) * D_ + ks * 32 + q * 8);

  float e[2][4] = {};
  for (int jt = 0; jt < 8; jt++) {
    const int j0 = jc * 512 + jt * 64;
    f32x4 acc[2][4];
#pragma unroll
    for (int si = 0; si < 2; si++)
#pragma unroll
      for (int tj = 0; tj < 4; tj++) acc[si][tj] = (f32x4){0.f, 0.f, 0.f, 0.f};
#pragma unroll
    for (int tj = 0; tj < 4; tj++) {
      bf16x8 b[4];
#pragma unroll
      for (int ks = 0; ks < 4; ks++)
        b[ks] = *(const bf16x8*)(Zm + (size_t)(j0 + tj * 16 + ln) * D_ + ks * 32 + q * 8);
#pragma unroll
      for (int ks = 0; ks < 4; ks++) {
        acc[0][tj] = __builtin_amdgcn_mfma_f32_16x16x32_bf16(a[0][ks], b[ks], acc[0][tj], 0, 0, 0);
        acc[1][tj] = __builtin_amdgcn_mfma_f32_16x16x32_bf16(a[1][ks], b[ks], acc[1][tj], 0, 0, 0);
      }
    }
#pragma unroll
    for (int si = 0; si < 2; si++)
#pragma unroll
      for (int reg = 0; reg < 4; reg++) {
        float s = 0.f;
#pragma unroll
        for (int tj = 0; tj < 4; tj++) s += __expf(acc[si][tj][reg] * INV_T);
        e[si][reg] += s;
      }
  }
  // reduce across the 16 lanes sharing q; rows i0 + si*16 + q*4 + reg
#pragma unroll
  for (int si = 0; si < 2; si++)
#pragma unroll
    for (int reg = 0; reg < 4; reg++) {
#pragma unroll
      for (int off = 8; off > 0; off >>= 1)
        e[si][reg] += __shfl_xor(e[si][reg], off, 16);
    }
  if (ln == 0) {
#pragma unroll
    for (int si = 0; si < 2; si++)
#pragma unroll
      for (int reg = 0; reg < 4; reg++)
        rsP[((size_t)m * 8 + jc) * B_ + i0 + si * 16 + q * 4 + reg] = e[si][reg];
  }
}

// ---------------- pos (wave-per-pair, 4 pairs/block) ----------------
__global__ __launch_bounds__(256) void pos_kernel(const float* __restrict__ z,
                                                  float* __restrict__ pos) {
  const int p = blockIdx.x * 4 + (threadIdx.x >> 6);   // p over S_*B_
  const int lane = threadIdx.x & 63;
  const int s = p >> 12, b = p & (B_ - 1);
  float2 v1 = *(const float2*)(z + (size_t)b * D_ + lane * 2);
  float2 v2 = *(const float2*)(z + (size_t)((1 + s) * B_ + b) * D_ + lane * 2);
  float t = waveXorSum(v1.x * v2.x + v1.y * v2.y);
  if (lane == 0) pos[s * B_ + b] = t;
}

// ---------------- codebook loss stage 1 ----------------
__global__ __launch_bounds__(128) void cbsum_kernel(const float* __restrict__ cb,
                                                    const float* __restrict__ cbn2,
                                                    float* __restrict__ cbsum) {
  const int m = blockIdx.x >> 3;
  const int k0 = (blockIdx.x & 7) * 64;
  const int d = threadIdx.x;
  float acc = 0.0f;
  for (int k = k0; k < k0 + 64; k++) {
    float inv = 1.0f / fmaxf(sqrtf(cbn2[m * K_ + k]), EPS_);
    acc += cb[((size_t)m * K_ + k) * D_ + d] * inv;
  }
  atomicAdd(&cbsum[m * D_ + d], acc);
}

// ---------------- per-source loss reduce ----------------
__global__ __launch_bounds__(256) void lossred_kernel(const float* __restrict__ rsP,
                                                      const float* __restrict__ pos,
                                                      float* __restrict__ loss_acc) {
  const int s = blockIdx.y;
  const int i = blockIdx.x * 256 + threadIdx.x;
  __shared__ float red[4];
  float denom = -EXP10;
#pragma unroll
  for (int jc = 0; jc < 8; jc++) {
    denom += rsP[(size_t)jc * B_ + i];                      // m = 0 (refl)
    denom += rsP[((size_t)(1 + s) * 8 + jc) * B_ + i];      // m = 1+s
  }
  float val = logf(denom) - pos[s * B_ + i] * INV_T;
  float v = waveReduceSum(val);
  if ((threadIdx.x & 63) == 0) red[threadIdx.x >> 6] = v;
  __syncthreads();
  if (threadIdx.x == 0) atomicAdd(&loss_acc[s], red[0] + red[1] + red[2] + red[3]);
}

// ---------------- finalize ----------------
__global__ __launch_bounds__(128) void finalize_kernel(const float* __restrict__ cbsum,
                                                       const float* __restrict__ loss_acc,
                                                       float* __restrict__ out) {
  const int d = threadIdx.x;
  __shared__ float red[2];
  float acc = 0.0f;
#pragma unroll
  for (int m = 0; m < C_; m++) {
    float v = cbsum[m * D_ + d];
    acc += v * v;
  }
  float tot = blockReduceSum128(acc, red);
  if (d == 0) out[0] = tot * (1.0f / (3.0f * 512.0f * 512.0f));
  if (d == 1) out[1] = 0.0f;
  if (d >= 2 && d < 5) out[d] = loss_acc[d - 2] * (1.0f / 4096.0f);
}

extern "C" void kernel_launch(void* const* d_in, const int* in_sizes, int n_in,
                              void* d_out, int out_size, void* d_ws, size_t ws_size,
                              hipStream_t stream) {
  const float* x    = (const float*)d_in[0];
  const float* w1   = (const float*)d_in[1];
  const float* b1   = (const float*)d_in[2];
  const float* w2   = (const float*)d_in[3];
  const float* b2   = (const float*)d_in[4];
  const float* w3   = (const float*)d_in[5];
  const float* b3   = (const float*)d_in[6];
  const float* w4   = (const float*)d_in[7];
  const float* b4   = (const float*)d_in[8];
  const float* qw1  = (const float*)d_in[9];
  const float* qb1  = (const float*)d_in[10];
  const float* qw2  = (const float*)d_in[11];
  const float* cb   = (const float*)d_in[12];
  float* out = (float*)d_out;
  char* base = (char*)d_ws;

  size_t o = 0;
  auto alloc = [&](size_t bytes) { size_t r = o; o += (bytes + 255) & ~(size_t)255; return r; };
  size_t o_xb   = alloc((size_t)S_ * B_ * DIN_ * 2);
  size_t o_wt1  = alloc((size_t)S_ * H1_ * DIN_ * 2);
  size_t o_wt2  = alloc((size_t)S_ * H2_ * H1_ * 2);
  size_t o_wt3  = alloc((size_t)S_ * H3_ * H2_ * 2);
  size_t o_wt4  = alloc((size_t)S_ * D_ * H3_ * 2);
  size_t o_h1b  = alloc((size_t)S_ * B_ * H1_ * 2);
  size_t o_h2b  = alloc((size_t)S_ * B_ * H2_ * 2);
  size_t o_h3b  = alloc((size_t)S_ * B_ * H3_ * 2);
  size_t o_emb  = alloc((size_t)S_ * B_ * D_ * 4);
  size_t o_scr  = alloc((size_t)S_ * B_ * 4);
  size_t o_fus  = alloc((size_t)B_ * D_ * 4);
  size_t o_qs   = alloc((size_t)B_ * D_ * 4);
  size_t o_z    = alloc((size_t)4 * B_ * D_ * 4);
  size_t o_zb   = alloc((size_t)4 * B_ * D_ * 2);
  size_t o_cbn2 = alloc((size_t)C_ * K_ * 4);
  size_t o_cbb  = alloc((size_t)C_ * K_ * D_ * 2);
  size_t o_rsP  = alloc((size_t)4 * 8 * B_ * 4);
  size_t o_lacc = alloc(64);
  size_t o_cbs  = alloc((size_t)C_ * D_ * 4);
  size_t o_pos  = alloc((size_t)S_ * B_ * 4);
  (void)ws_size; (void)in_sizes; (void)n_in; (void)out_size;

  unsigned short* xb  = (unsigned short*)(base + o_xb);
  unsigned short* wt1 = (unsigned short*)(base + o_wt1);
  unsigned short* wt2 = (unsigned short*)(base + o_wt2);
  unsigned short* wt3 = (unsigned short*)(base + o_wt3);
  unsigned short* wt4 = (unsigned short*)(base + o_wt4);
  unsigned short* h1b = (unsigned short*)(base + o_h1b);
  unsigned short* h2b = (unsigned short*)(base + o_h2b);
  unsigned short* h3b = (unsigned short*)(base + o_h3b);
  float* emb   = (float*)(base + o_emb);
  float* score = (float*)(base + o_scr);
  float* fused = (float*)(base + o_fus);
  float* qsum  = (float*)(base + o_qs);
  float* z     = (float*)(base + o_z);
  unsigned short* zb = (unsigned short*)(base + o_zb);
  float* cbn2  = (float*)(base + o_cbn2);
  unsigned short* cbb = (unsigned short*)(base + o_cbb);
  float* rsP   = (float*)(base + o_rsP);
  float* lacc  = (float*)(base + o_lacc);
  float* cbsum = (float*)(base + o_cbs);
  float* pos   = (float*)(base + o_pos);

  hipMemsetAsync(lacc, 0, 64, stream);
  hipMemsetAsync(cbsum, 0, (size_t)C_ * D_ * 4, stream);

  // input + weight conversion
  cvt_bf16_kernel<<<dim3((S_ * B_ * DIN_) / 1024), 256, 0, stream>>>(x, xb, S_ * B_ * DIN_);
  cvt_bf16_kernel<<<dim3((C_ * K_ * D_) / 1024), 256, 0, stream>>>(cb, cbb, C_ * K_ * D_);
  transpose_w_kernel<<<dim3(DIN_ / 32, H1_ / 32, S_), dim3(32, 8), 0, stream>>>(w1, wt1, DIN_, H1_);
  transpose_w_kernel<<<dim3(H1_ / 32, H2_ / 32, S_), dim3(32, 8), 0, stream>>>(w2, wt2, H1_, H2_);
  transpose_w_kernel<<<dim3(H2_ / 32, H3_ / 32, S_), dim3(32, 8), 0, stream>>>(w3, wt3, H2_, H3_);
  transpose_w_kernel<<<dim3(H3_ / 32, D_ / 32, S_), dim3(32, 8), 0, stream>>>(w4, wt4, H3_, D_);

  // encoder MLP via LDS-staged MFMA (BK=64)
  const int Mtot = S_ * B_;
  gemm_lds_kernel<<<dim3(H1_ / 128, Mtot / 64), 256, 0, stream>>>(xb, wt1, b1, h1b, DIN_, H1_, 1, 0);
  gemm_lds_kernel<<<dim3(H2_ / 128, Mtot / 64), 256, 0, stream>>>(h1b, wt2, b2, h2b, H1_, H2_, 1, 0);
  gemm_lds_kernel<<<dim3(H3_ / 128, Mtot / 64), 256, 0, stream>>>(h2b, wt3, b3, h3b, H2_, H3_, 1, 0);
  gemm_lds_kernel<<<dim3(D_ / 128, Mtot / 64), 256, 0, stream>>>(h3b, wt4, b4, emb, H3_, D_, 0, 1);

  // attention fusion
  score_kernel<<<dim3(B_ / 4), 256, 0, stream>>>(emb, qw1, qb1, qw2, score);
  fuse_kernel<<<dim3(B_), 128, 0, stream>>>(emb, score, fused);

  // residual VQ (MFMA distance GEMM)
  cbnorm2_kernel<<<dim3(C_ * K_), 64, 0, stream>>>(cb, cbn2);
  vq_mfma_kernel<<<dim3(B_ / 16), 512, 0, stream>>>(fused, cb, cbb, cbn2, qsum);

  // normalize (fp32 z + bf16 zb), wave per row
  normalize_kernel<<<dim3(4 * B_ / 4), 256, 0, stream>>>(qsum, emb, z, zb);

  // contrastive rowsum partials + pos
  contrast_mfma_kernel<<<dim3(8, 32, 4), 256, 0, stream>>>(zb, rsP);
  pos_kernel<<<dim3(S_ * B_ / 4), 256, 0, stream>>>(z, pos);

  // codebook loss stage 1
  cbsum_kernel<<<dim3(C_ * 8), 128, 0, stream>>>(cb, cbn2, cbsum);

  // per-source contrastive means
  lossred_kernel<<<dim3(B_ / 256, S_), 256, 0, stream>>>(rsP, pos, lacc);

  finalize_kernel<<<dim3(1), 128, 0, stream>>>(cbsum, lacc, out);
}

// Round 10
// 270.570 us; speedup vs baseline: 1.1659x; 1.1659x over previous
//
#include <hip/hip_runtime.h>
#include <hip/hip_bf16.h>

// Problem constants
#define S_   3
#define B_   4096
#define DIN_ 1024
#define H1_  512
#define H2_  384
#define H3_  256
#define D_   128
#define K_   512
#define C_   3
#define INV_T 10.0f          // 1/TEMP
#define EPS_  1e-12f
#define EXP10 22026.465794806718f   // exp(1/T), diag(refl) analytically

typedef float f32x4 __attribute__((ext_vector_type(4)));
typedef short bf16x8 __attribute__((ext_vector_type(8)));

__device__ __forceinline__ unsigned short f2bf(float f) {
  unsigned int u = __float_as_uint(f);
  u = (u + 0x7FFF + ((u >> 16) & 1)) >> 16;   // round-to-nearest-even
  return (unsigned short)u;
}

// ---------------- reduction helpers ----------------
__device__ __forceinline__ float waveReduceSum(float v) {
#pragma unroll
  for (int off = 32; off > 0; off >>= 1) v += __shfl_down(v, off, 64);
  return v;
}

__device__ __forceinline__ float waveXorSum(float v) {
#pragma unroll
  for (int off = 32; off > 0; off >>= 1) v += __shfl_xor(v, off, 64);
  return v;
}

__device__ __forceinline__ float blockReduceSum128(float v, float* sbuf) {
  v = waveReduceSum(v);
  if ((threadIdx.x & 63) == 0) sbuf[threadIdx.x >> 6] = v;
  __syncthreads();
  float r = sbuf[0] + sbuf[1];
  __syncthreads();
  return r;
}

// ---------------- fp32 -> bf16 elementwise (n % 1024 == 0) ----------------
__global__ __launch_bounds__(256) void cvt_bf16_kernel(const float* __restrict__ in,
                                                       unsigned short* __restrict__ out,
                                                       int n) {
  int i = (blockIdx.x * 256 + threadIdx.x) * 4;
  if (i < n) {
    float4 v = *(const float4*)(in + i);
    out[i + 0] = f2bf(v.x); out[i + 1] = f2bf(v.y);
    out[i + 2] = f2bf(v.z); out[i + 3] = f2bf(v.w);
  }
}

// ---------------- W[S][K][N] fp32 -> Wt[S][N][K] bf16 ------
__global__ __launch_bounds__(256) void transpose_w_kernel(const float* __restrict__ W,
                                                          unsigned short* __restrict__ Wt,
                                                          int K, int N) {
  const int s = blockIdx.z;
  const int k0 = blockIdx.x * 32, n0 = blockIdx.y * 32;
  const int tx = threadIdx.x, ty = threadIdx.y;
  __shared__ float t[32][33];
  const float* Ws = W + (size_t)s * K * N;
  unsigned short* Wts = Wt + (size_t)s * N * K;
#pragma unroll
  for (int i = 0; i < 4; i++)
    t[ty + 8 * i][tx] = Ws[(size_t)(k0 + ty + 8 * i) * N + n0 + tx];
  __syncthreads();
#pragma unroll
  for (int i = 0; i < 4; i++)
    Wts[(size_t)(n0 + ty + 8 * i) * K + k0 + tx] = f2bf(t[tx][ty + 8 * i]);
}

// ---------------- LDS-staged MFMA GEMM, BK=64, register-pipelined ----------------
__global__ __launch_bounds__(256) void gemm_lds_kernel(
    const unsigned short* __restrict__ A, const unsigned short* __restrict__ Wt,
    const float* __restrict__ bias, void* __restrict__ Y,
    int K, int N, int relu, int out_f32) {
  const int t = threadIdx.x;
  const int lane = t & 63;
  const int w = t >> 6;
  const int ln = lane & 15, q = lane >> 4;
  const int wm = w >> 1, wn = w & 1;
  const int n0 = blockIdx.x * 128;
  const int mblk = blockIdx.y;
  const int s = mblk >> 6;                  // 4096/64 = 64 m-blocks per source
  const int m0 = mblk * 64;

  const unsigned short* Ag = A + (size_t)m0 * K;
  const unsigned short* Bg = Wt + (size_t)s * N * K + (size_t)n0 * K;
  const float* bs = bias + (size_t)s * N;

  __shared__ unsigned short Asm[2 * 64 * 32];    // two 32-k halves, 64B rows
  __shared__ unsigned short Bsm[2 * 128 * 32];

  const int arow0 = t >> 3, ak8 = t & 7;
  const int aL0 = (ak8 >> 2) * 2048 + arow0 * 32 + (ak8 & 3) * 8;
  const int bL0 = (ak8 >> 2) * 4096 + arow0 * 32 + (ak8 & 3) * 8;
  const size_t gA0 = (size_t)arow0 * K + ak8 * 8;

  bf16x8 ra0 = *(const bf16x8*)(Ag + gA0);
  bf16x8 ra1 = *(const bf16x8*)(Ag + gA0 + (size_t)32 * K);
  bf16x8 rb0 = *(const bf16x8*)(Bg + gA0);
  bf16x8 rb1 = *(const bf16x8*)(Bg + gA0 + (size_t)32 * K);
  bf16x8 rb2 = *(const bf16x8*)(Bg + gA0 + (size_t)64 * K);
  bf16x8 rb3 = *(const bf16x8*)(Bg + gA0 + (size_t)96 * K);

  f32x4 acc[2][4];
#pragma unroll
  for (int i = 0; i < 2; i++)
#pragma unroll
    for (int j = 0; j < 4; j++) acc[i][j] = (f32x4){0.f, 0.f, 0.f, 0.f};

  for (int k0 = 0; k0 < K; k0 += 64) {
    *(bf16x8*)&Asm[aL0] = ra0;
    *(bf16x8*)&Asm[aL0 + 1024] = ra1;
    *(bf16x8*)&Bsm[bL0] = rb0;
    *(bf16x8*)&Bsm[bL0 + 1024] = rb1;
    *(bf16x8*)&Bsm[bL0 + 2048] = rb2;
    *(bf16x8*)&Bsm[bL0 + 3072] = rb3;
    __syncthreads();
    if (k0 + 64 < K) {
      const size_t g = gA0 + k0 + 64;
      ra0 = *(const bf16x8*)(Ag + g);
      ra1 = *(const bf16x8*)(Ag + g + (size_t)32 * K);
      rb0 = *(const bf16x8*)(Bg + g);
      rb1 = *(const bf16x8*)(Bg + g + (size_t)32 * K);
      rb2 = *(const bf16x8*)(Bg + g + (size_t)64 * K);
      rb3 = *(const bf16x8*)(Bg + g + (size_t)96 * K);
    }
    bf16x8 af[2][2], bf[4][2];
#pragma unroll
    for (int ti = 0; ti < 2; ti++)
#pragma unroll
      for (int ksl = 0; ksl < 2; ksl++)
        af[ti][ksl] = *(const bf16x8*)&Asm[ksl * 2048 + (wm * 32 + ti * 16 + ln) * 32 + q * 8];
#pragma unroll
    for (int tj = 0; tj < 4; tj++)
#pragma unroll
      for (int ksl = 0; ksl < 2; ksl++)
        bf[tj][ksl] = *(const bf16x8*)&Bsm[ksl * 4096 + (wn * 64 + tj * 16 + ln) * 32 + q * 8];
#pragma unroll
    for (int ksl = 0; ksl < 2; ksl++)
#pragma unroll
      for (int ti = 0; ti < 2; ti++)
#pragma unroll
        for (int tj = 0; tj < 4; tj++)
          acc[ti][tj] = __builtin_amdgcn_mfma_f32_16x16x32_bf16(af[ti][ksl], bf[tj][ksl], acc[ti][tj], 0, 0, 0);
    __syncthreads();
  }

#pragma unroll
  for (int ti = 0; ti < 2; ti++)
#pragma unroll
    for (int tj = 0; tj < 4; tj++) {
      const int cc = n0 + wn * 64 + tj * 16 + ln;
      const float bv = bs[cc];
#pragma unroll
      for (int reg = 0; reg < 4; reg++) {
        const int r = m0 + wm * 32 + ti * 16 + q * 4 + reg;
        float v = acc[ti][tj][reg] + bv;
        if (relu) v = fmaxf(v, 0.0f);
        if (out_f32) ((float*)Y)[(size_t)r * N + cc] = v;
        else ((unsigned short*)Y)[(size_t)r * N + cc] = f2bf(v);
      }
    }
}

// ---------------- attention score, batched: block = 4 b x 3 s rows ----------------
__global__ __launch_bounds__(256) void score_kernel(
    const float* __restrict__ emb, const float* __restrict__ qw1,
    const float* __restrict__ qb1, const float* __restrict__ qw2,
    float* __restrict__ score) {
  const int b0 = blockIdx.x * 4;
  const int t = threadIdx.x;
  const int g = t >> 7, d = t & 127;
  __shared__ float e[12][D_];
  __shared__ float red[4][6];
#pragma unroll
  for (int i = 0; i < 3; i++) {
    int idx = i * 512 + t * 2;
    int r = idx >> 7, dd = idx & 127;
    int s = r >> 2, bi = r & 3;
    *(float2*)&e[r][dd] = *(const float2*)(emb + ((size_t)(s * B_ + b0 + bi)) * D_ + dd);
  }
  __syncthreads();
  float acc[6] = {0.f, 0.f, 0.f, 0.f, 0.f, 0.f};
  for (int i = 0; i < D_; i++) {
    float w = qw1[i * D_ + d];
#pragma unroll
    for (int j = 0; j < 6; j++) acc[j] = fmaf(e[g * 6 + j][i], w, acc[j]);
  }
  const float qb = qb1[d], q2 = qw2[d];
  float val[6];
#pragma unroll
  for (int j = 0; j < 6; j++) val[j] = tanhf(acc[j] + qb) * q2;
  const int wave = t >> 6;
#pragma unroll
  for (int j = 0; j < 6; j++) {
    float v = waveReduceSum(val[j]);
    if ((t & 63) == 0) red[wave][j] = v;
  }
  __syncthreads();
  if (t < 12) {
    int gg = t / 6, j = t % 6;
    int r = gg * 6 + j;
    int s = r >> 2, bi = r & 3;
    score[s * B_ + b0 + bi] = red[2 * gg][j] + red[2 * gg + 1][j];
  }
}

// ---------------- softmax over S + fuse ----------------
__global__ __launch_bounds__(128) void fuse_kernel(
    const float* __restrict__ emb, const float* __restrict__ score,
    float* __restrict__ fused) {
  const int b = blockIdx.x, d = threadIdx.x;
  float s0 = score[0 * B_ + b], s1 = score[1 * B_ + b], s2 = score[2 * B_ + b];
  float mx = fmaxf(s0, fmaxf(s1, s2));
  float e0 = __expf(s0 - mx), e1 = __expf(s1 - mx), e2 = __expf(s2 - mx);
  float inv = 1.0f / (e0 + e1 + e2);
  fused[(long long)b * D_ + d] =
      e0 * inv * emb[(long long)(0 * B_ + b) * D_ + d] +
      e1 * inv * emb[(long long)(1 * B_ + b) * D_ + d] +
      e2 * inv * emb[(long long)(2 * B_ + b) * D_ + d];
}

// ---------------- codebook squared norms ----------------
__global__ __launch_bounds__(64) void cbnorm2_kernel(const float* __restrict__ cb,
                                                     float* __restrict__ cbn2) {
  const int r = blockIdx.x, lane = threadIdx.x;
  const float* row = cb + (long long)r * D_;
  float v0 = row[lane], v1 = row[lane + 64];
  float t = waveReduceSum(v0 * v0 + v1 * v1);
  if (lane == 0) cbn2[r] = t;
}

// ---------------- residual VQ v3: MFMA distance GEMM ----------------
__global__ __launch_bounds__(512) void vq_mfma_kernel(
    const float* __restrict__ fused, const float* __restrict__ cb,
    const unsigned short* __restrict__ cbb, const float* __restrict__ cbn2,
    float* __restrict__ qsum) {
  const int r0 = blockIdx.x * 16;
  const int t = threadIdx.x;
  const int w = t >> 6, lane = t & 63;
  const int ln = lane & 15, q = lane >> 4;
  __shared__ float resv[16][D_];
  __shared__ unsigned short resb[16][D_];
  __shared__ float candd[8][16];
  __shared__ int candk[8][16];
  __shared__ int bestk[16];

  {
    int idx = t * 4;
    int r = idx >> 7, dd = idx & 127;
    float4 v = *(const float4*)(fused + (size_t)(r0 + r) * D_ + dd);
    *(float4*)&resv[r][dd] = v;
    resb[r][dd + 0] = f2bf(v.x); resb[r][dd + 1] = f2bf(v.y);
    resb[r][dd + 2] = f2bf(v.z); resb[r][dd + 3] = f2bf(v.w);
  }
  __syncthreads();

  for (int c = 0; c < C_; c++) {
    bf16x8 a[4];
#pragma unroll
    for (int ks = 0; ks < 4; ks++)
      a[ks] = *(const bf16x8*)&resb[ln][ks * 32 + q * 8];
    f32x4 acc[4];
#pragma unroll
    for (int tt = 0; tt < 4; tt++) acc[tt] = (f32x4){0.f, 0.f, 0.f, 0.f};
#pragma unroll
    for (int tt = 0; tt < 4; tt++) {
      const int n = w * 64 + tt * 16 + ln;
      const unsigned short* bp = cbb + ((size_t)c * K_ + n) * D_;
#pragma unroll
      for (int ks = 0; ks < 4; ks++) {
        bf16x8 b = *(const bf16x8*)(bp + ks * 32 + q * 8);
        acc[tt] = __builtin_amdgcn_mfma_f32_16x16x32_bf16(a[ks], b, acc[tt], 0, 0, 0);
      }
    }
    float bd[4]; int bk[4];
#pragma unroll
    for (int reg = 0; reg < 4; reg++) { bd[reg] = 3.4e38f; bk[reg] = 0x7fffffff; }
#pragma unroll
    for (int tt = 0; tt < 4; tt++) {
      const int col = w * 64 + tt * 16 + ln;
      const float n2 = cbn2[c * K_ + col];
#pragma unroll
      for (int reg = 0; reg < 4; reg++) {
        float dist = n2 - 2.0f * acc[tt][reg];
        if (dist < bd[reg] || (dist == bd[reg] && col < bk[reg])) { bd[reg] = dist; bk[reg] = col; }
      }
    }
#pragma unroll
    for (int reg = 0; reg < 4; reg++) {
#pragma unroll
      for (int off = 8; off > 0; off >>= 1) {
        float d1 = __shfl_down(bd[reg], off, 16);
        int k1 = __shfl_down(bk[reg], off, 16);
        if (d1 < bd[reg] || (d1 == bd[reg] && k1 < bk[reg])) { bd[reg] = d1; bk[reg] = k1; }
      }
      if (ln == 0) { candd[w][q * 4 + reg] = bd[reg]; candk[w][q * 4 + reg] = bk[reg]; }
    }
    __syncthreads();
    if (w == 0) {
      int row = lane >> 2, g = lane & 3;
      float d0 = candd[2 * g][row]; int k0 = candk[2 * g][row];
      float d1 = candd[2 * g + 1][row]; int k1 = candk[2 * g + 1][row];
      if (d1 < d0 || (d1 == d0 && k1 < k0)) { d0 = d1; k0 = k1; }
#pragma unroll
      for (int off = 2; off > 0; off >>= 1) {
        float dn = __shfl_down(d0, off, 4);
        int kn = __shfl_down(k0, off, 4);
        if (dn < d0 || (dn == d0 && kn < k0)) { d0 = dn; k0 = kn; }
      }
      if (g == 0) bestk[row] = k0;
    }
    __syncthreads();
    {
      int idx = t * 4;
      int r = idx >> 7, dd = idx & 127;
      const float4 qv = *(const float4*)(cb + ((size_t)c * K_ + bestk[r]) * D_ + dd);
      float4 rv = *(float4*)&resv[r][dd];
      rv.x -= qv.x; rv.y -= qv.y; rv.z -= qv.z; rv.w -= qv.w;
      *(float4*)&resv[r][dd] = rv;
      resb[r][dd + 0] = f2bf(rv.x); resb[r][dd + 1] = f2bf(rv.y);
      resb[r][dd + 2] = f2bf(rv.z); resb[r][dd + 3] = f2bf(rv.w);
    }
    __syncthreads();
  }

  {
    int idx = t * 4;
    int r = idx >> 7, dd = idx & 127;
    float4 f = *(const float4*)(fused + (size_t)(r0 + r) * D_ + dd);
    float4 rv = *(float4*)&resv[r][dd];
    f.x -= rv.x; f.y -= rv.y; f.z -= rv.z; f.w -= rv.w;
    *(float4*)(qsum + (size_t)(r0 + r) * D_ + dd) = f;
  }
}

// ---------------- normalize rows + bf16 copy (wave-per-row, 4 rows/block) --------
__global__ __launch_bounds__(256) void normalize_kernel(
    const float* __restrict__ qsum, const float* __restrict__ emb,
    float* __restrict__ z, unsigned short* __restrict__ zb) {
  const int g = blockIdx.x * 4 + (threadIdx.x >> 6);
  const int lane = threadIdx.x & 63;
  const float* src = (g < B_) ? (qsum + (size_t)g * D_) : (emb + (size_t)(g - B_) * D_);
  float2 v = *(const float2*)(src + lane * 2);
  float n2 = waveXorSum(v.x * v.x + v.y * v.y);
  float inv = 1.0f / fmaxf(sqrtf(n2), EPS_);
  float zx = v.x * inv, zy = v.y * inv;
  *(float2*)(z + (size_t)g * D_ + lane * 2) = make_float2(zx, zy);
  zb[(size_t)g * D_ + lane * 2 + 0] = f2bf(zx);
  zb[(size_t)g * D_ + lane * 2 + 1] = f2bf(zy);
}

// ---------------- contrastive exp-rowsums v4: LDS-staged B tiles ----------------
// grid (4 jc, 32 ib, 4 m) = 512 blocks. Block = 128 i (4 waves x 32 i); jt loop
// over 16 j-tiles of 64. Each 16 KB Zm j-tile (contiguous rows) is staged into
// LDS with coalesced loads (+8-short row pad -> 2-way bank alias, free), then
// B-fragments come from ds_read_b128 instead of 16-line-scattered global loads.
// Register prefetch of tile jt+1 between the two barriers (gemm_lds pattern).
__global__ __launch_bounds__(256) void contrast_mfma_kernel(
    const unsigned short* __restrict__ zb, float* __restrict__ rsP) {
  const int jc = blockIdx.x, ib = blockIdx.y, m = blockIdx.z;
  const int t = threadIdx.x;
  const int w = t >> 6, lane = t & 63;
  const int ln = lane & 15, q = lane >> 4;
  const int i0 = ib * 128 + w * 32;
  const unsigned short* Za = zb;
  const unsigned short* Zm = zb + (size_t)m * B_ * D_;

  __shared__ unsigned short Zsm[64 * 136];   // 64 j-rows, 128 data + 8 pad shorts

  // A-fragments: wave-resident (scattered load, once per block)
  bf16x8 a[2][4];
#pragma unroll
  for (int si = 0; si < 2; si++)
#pragma unroll
    for (int ks = 0; ks < 4; ks++)
      a[si][ks] = *(const bf16x8*)(Za + (size_t)(i0 + si * 16 + ln) * D_ + ks * 32 + q * 8);

  // preload tile 0: chunk c = t + p*256 -> global shorts j0*128 + c*8 (coalesced)
  const unsigned short* tb = Zm + (size_t)(jc * 1024) * D_;
  bf16x8 rz[4];
#pragma unroll
  for (int p = 0; p < 4; p++)
    rz[p] = *(const bf16x8*)(tb + t * 8 + p * 2048);

  float e[2][4] = {};
  for (int jt = 0; jt < 16; jt++) {
    // stage regs -> LDS (row = c>>4, ch = c&15; padded row stride 136)
#pragma unroll
    for (int p = 0; p < 4; p++) {
      int c = t + p * 256;
      *(bf16x8*)&Zsm[(c >> 4) * 136 + (c & 15) * 8] = rz[p];
    }
    __syncthreads();
    if (jt + 1 < 16) {
      const unsigned short* tn = Zm + (size_t)(jc * 1024 + (jt + 1) * 64) * D_;
#pragma unroll
      for (int p = 0; p < 4; p++)
        rz[p] = *(const bf16x8*)(tn + t * 8 + p * 2048);
    }
    // compute from LDS
    f32x4 acc[2][4];
#pragma unroll
    for (int si = 0; si < 2; si++)
#pragma unroll
      for (int tj = 0; tj < 4; tj++) acc[si][tj] = (f32x4){0.f, 0.f, 0.f, 0.f};
#pragma unroll
    for (int tj = 0; tj < 4; tj++) {
      bf16x8 b[4];
#pragma unroll
      for (int ks = 0; ks < 4; ks++)
        b[ks] = *(const bf16x8*)&Zsm[(tj * 16 + ln) * 136 + ks * 32 + q * 8];
#pragma unroll
      for (int ks = 0; ks < 4; ks++) {
        acc[0][tj] = __builtin_amdgcn_mfma_f32_16x16x32_bf16(a[0][ks], b[ks], acc[0][tj], 0, 0, 0);
        acc[1][tj] = __builtin_amdgcn_mfma_f32_16x16x32_bf16(a[1][ks], b[ks], acc[1][tj], 0, 0, 0);
      }
    }
#pragma unroll
    for (int si = 0; si < 2; si++)
#pragma unroll
      for (int reg = 0; reg < 4; reg++) {
        float s = 0.f;
#pragma unroll
        for (int tj = 0; tj < 4; tj++) s += __expf(acc[si][tj][reg] * INV_T);
        e[si][reg] += s;
      }
    __syncthreads();
  }
  // reduce across the 16 lanes sharing q; rows i0 + si*16 + q*4 + reg
#pragma unroll
  for (int si = 0; si < 2; si++)
#pragma unroll
    for (int reg = 0; reg < 4; reg++) {
#pragma unroll
      for (int off = 8; off > 0; off >>= 1)
        e[si][reg] += __shfl_xor(e[si][reg], off, 16);
    }
  if (ln == 0) {
#pragma unroll
    for (int si = 0; si < 2; si++)
#pragma unroll
      for (int reg = 0; reg < 4; reg++)
        rsP[((size_t)m * 4 + jc) * B_ + i0 + si * 16 + q * 4 + reg] = e[si][reg];
  }
}

// ---------------- pos (wave-per-pair, 4 pairs/block) ----------------
__global__ __launch_bounds__(256) void pos_kernel(const float* __restrict__ z,
                                                  float* __restrict__ pos) {
  const int p = blockIdx.x * 4 + (threadIdx.x >> 6);   // p over S_*B_
  const int lane = threadIdx.x & 63;
  const int s = p >> 12, b = p & (B_ - 1);
  float2 v1 = *(const float2*)(z + (size_t)b * D_ + lane * 2);
  float2 v2 = *(const float2*)(z + (size_t)((1 + s) * B_ + b) * D_ + lane * 2);
  float t = waveXorSum(v1.x * v2.x + v1.y * v2.y);
  if (lane == 0) pos[s * B_ + b] = t;
}

// ---------------- codebook loss stage 1 ----------------
__global__ __launch_bounds__(128) void cbsum_kernel(const float* __restrict__ cb,
                                                    const float* __restrict__ cbn2,
                                                    float* __restrict__ cbsum) {
  const int m = blockIdx.x >> 3;
  const int k0 = (blockIdx.x & 7) * 64;
  const int d = threadIdx.x;
  float acc = 0.0f;
  for (int k = k0; k < k0 + 64; k++) {
    float inv = 1.0f / fmaxf(sqrtf(cbn2[m * K_ + k]), EPS_);
    acc += cb[((size_t)m * K_ + k) * D_ + d] * inv;
  }
  atomicAdd(&cbsum[m * D_ + d], acc);
}

// ---------------- per-source loss reduce ----------------
__global__ __launch_bounds__(256) void lossred_kernel(const float* __restrict__ rsP,
                                                      const float* __restrict__ pos,
                                                      float* __restrict__ loss_acc) {
  const int s = blockIdx.y;
  const int i = blockIdx.x * 256 + threadIdx.x;
  __shared__ float red[4];
  float denom = -EXP10;
#pragma unroll
  for (int jc = 0; jc < 4; jc++) {
    denom += rsP[(size_t)jc * B_ + i];                      // m = 0 (refl)
    denom += rsP[((size_t)(1 + s) * 4 + jc) * B_ + i];      // m = 1+s
  }
  float val = logf(denom) - pos[s * B_ + i] * INV_T;
  float v = waveReduceSum(val);
  if ((threadIdx.x & 63) == 0) red[threadIdx.x >> 6] = v;
  __syncthreads();
  if (threadIdx.x == 0) atomicAdd(&loss_acc[s], red[0] + red[1] + red[2] + red[3]);
}

// ---------------- finalize ----------------
__global__ __launch_bounds__(128) void finalize_kernel(const float* __restrict__ cbsum,
                                                       const float* __restrict__ loss_acc,
                                                       float* __restrict__ out) {
  const int d = threadIdx.x;
  __shared__ float red[2];
  float acc = 0.0f;
#pragma unroll
  for (int m = 0; m < C_; m++) {
    float v = cbsum[m * D_ + d];
    acc += v * v;
  }
  float tot = blockReduceSum128(acc, red);
  if (d == 0) out[0] = tot * (1.0f / (3.0f * 512.0f * 512.0f));
  if (d == 1) out[1] = 0.0f;
  if (d >= 2 && d < 5) out[d] = loss_acc[d - 2] * (1.0f / 4096.0f);
}

extern "C" void kernel_launch(void* const* d_in, const int* in_sizes, int n_in,
                              void* d_out, int out_size, void* d_ws, size_t ws_size,
                              hipStream_t stream) {
  const float* x    = (const float*)d_in[0];
  const float* w1   = (const float*)d_in[1];
  const float* b1   = (const float*)d_in[2];
  const float* w2   = (const float*)d_in[3];
  const float* b2   = (const float*)d_in[4];
  const float* w3   = (const float*)d_in[5];
  const float* b3   = (const float*)d_in[6];
  const float* w4   = (const float*)d_in[7];
  const float* b4   = (const float*)d_in[8];
  const float* qw1  = (const float*)d_in[9];
  const float* qb1  = (const float*)d_in[10];
  const float* qw2  = (const float*)d_in[11];
  const float* cb   = (const float*)d_in[12];
  float* out = (float*)d_out;
  char* base = (char*)d_ws;

  size_t o = 0;
  auto alloc = [&](size_t bytes) { size_t r = o; o += (bytes + 255) & ~(size_t)255; return r; };
  size_t o_xb   = alloc((size_t)S_ * B_ * DIN_ * 2);
  size_t o_wt1  = alloc((size_t)S_ * H1_ * DIN_ * 2);
  size_t o_wt2  = alloc((size_t)S_ * H2_ * H1_ * 2);
  size_t o_wt3  = alloc((size_t)S_ * H3_ * H2_ * 2);
  size_t o_wt4  = alloc((size_t)S_ * D_ * H3_ * 2);
  size_t o_h1b  = alloc((size_t)S_ * B_ * H1_ * 2);
  size_t o_h2b  = alloc((size_t)S_ * B_ * H2_ * 2);
  size_t o_h3b  = alloc((size_t)S_ * B_ * H3_ * 2);
  size_t o_emb  = alloc((size_t)S_ * B_ * D_ * 4);
  size_t o_scr  = alloc((size_t)S_ * B_ * 4);
  size_t o_fus  = alloc((size_t)B_ * D_ * 4);
  size_t o_qs   = alloc((size_t)B_ * D_ * 4);
  size_t o_z    = alloc((size_t)4 * B_ * D_ * 4);
  size_t o_zb   = alloc((size_t)4 * B_ * D_ * 2);
  size_t o_cbn2 = alloc((size_t)C_ * K_ * 4);
  size_t o_cbb  = alloc((size_t)C_ * K_ * D_ * 2);
  size_t o_rsP  = alloc((size_t)4 * 4 * B_ * 4);
  size_t o_lacc = alloc(64);
  size_t o_cbs  = alloc((size_t)C_ * D_ * 4);
  size_t o_pos  = alloc((size_t)S_ * B_ * 4);
  (void)ws_size; (void)in_sizes; (void)n_in; (void)out_size;

  unsigned short* xb  = (unsigned short*)(base + o_xb);
  unsigned short* wt1 = (unsigned short*)(base + o_wt1);
  unsigned short* wt2 = (unsigned short*)(base + o_wt2);
  unsigned short* wt3 = (unsigned short*)(base + o_wt3);
  unsigned short* wt4 = (unsigned short*)(base + o_wt4);
  unsigned short* h1b = (unsigned short*)(base + o_h1b);
  unsigned short* h2b = (unsigned short*)(base + o_h2b);
  unsigned short* h3b = (unsigned short*)(base + o_h3b);
  float* emb   = (float*)(base + o_emb);
  float* score = (float*)(base + o_scr);
  float* fused = (float*)(base + o_fus);
  float* qsum  = (float*)(base + o_qs);
  float* z     = (float*)(base + o_z);
  unsigned short* zb = (unsigned short*)(base + o_zb);
  float* cbn2  = (float*)(base + o_cbn2);
  unsigned short* cbb = (unsigned short*)(base + o_cbb);
  float* rsP   = (float*)(base + o_rsP);
  float* lacc  = (float*)(base + o_lacc);
  float* cbsum = (float*)(base + o_cbs);
  float* pos   = (float*)(base + o_pos);

  hipMemsetAsync(lacc, 0, 64, stream);
  hipMemsetAsync(cbsum, 0, (size_t)C_ * D_ * 4, stream);

  // input + weight conversion
  cvt_bf16_kernel<<<dim3((S_ * B_ * DIN_) / 1024), 256, 0, stream>>>(x, xb, S_ * B_ * DIN_);
  cvt_bf16_kernel<<<dim3((C_ * K_ * D_) / 1024), 256, 0, stream>>>(cb, cbb, C_ * K_ * D_);
  transpose_w_kernel<<<dim3(DIN_ / 32, H1_ / 32, S_), dim3(32, 8), 0, stream>>>(w1, wt1, DIN_, H1_);
  transpose_w_kernel<<<dim3(H1_ / 32, H2_ / 32, S_), dim3(32, 8), 0, stream>>>(w2, wt2, H1_, H2_);
  transpose_w_kernel<<<dim3(H2_ / 32, H3_ / 32, S_), dim3(32, 8), 0, stream>>>(w3, wt3, H2_, H3_);
  transpose_w_kernel<<<dim3(H3_ / 32, D_ / 32, S_), dim3(32, 8), 0, stream>>>(w4, wt4, H3_, D_);

  // encoder MLP via LDS-staged MFMA (BK=64)
  const int Mtot = S_ * B_;
  gemm_lds_kernel<<<dim3(H1_ / 128, Mtot / 64), 256, 0, stream>>>(xb, wt1, b1, h1b, DIN_, H1_, 1, 0);
  gemm_lds_kernel<<<dim3(H2_ / 128, Mtot / 64), 256, 0, stream>>>(h1b, wt2, b2, h2b, H1_, H2_, 1, 0);
  gemm_lds_kernel<<<dim3(H3_ / 128, Mtot / 64), 256, 0, stream>>>(h2b, wt3, b3, h3b, H2_, H3_, 1, 0);
  gemm_lds_kernel<<<dim3(D_ / 128, Mtot / 64), 256, 0, stream>>>(h3b, wt4, b4, emb, H3_, D_, 0, 1);

  // attention fusion
  score_kernel<<<dim3(B_ / 4), 256, 0, stream>>>(emb, qw1, qb1, qw2, score);
  fuse_kernel<<<dim3(B_), 128, 0, stream>>>(emb, score, fused);

  // residual VQ (MFMA distance GEMM)
  cbnorm2_kernel<<<dim3(C_ * K_), 64, 0, stream>>>(cb, cbn2);
  vq_mfma_kernel<<<dim3(B_ / 16), 512, 0, stream>>>(fused, cb, cbb, cbn2, qsum);

  // normalize (fp32 z + bf16 zb), wave per row
  normalize_kernel<<<dim3(4 * B_ / 4), 256, 0, stream>>>(qsum, emb, z, zb);

  // contrastive rowsum partials + pos
  contrast_mfma_kernel<<<dim3(4, 32, 4), 256, 0, stream>>>(zb, rsP);
  pos_kernel<<<dim3(S_ * B_ / 4), 256, 0, stream>>>(z, pos);

  // codebook loss stage 1
  cbsum_kernel<<<dim3(C_ * 8), 128, 0, stream>>>(cb, cbn2, cbsum);

  // per-source contrastive means
  lossred_kernel<<<dim3(B_ / 256, S_), 256, 0, stream>>>(rsP, pos, lacc);

  finalize_kernel<<<dim3(1), 128, 0, stream>>>(cbsum, lacc, out);
}

// Round 11
// 257.870 us; speedup vs baseline: 1.2234x; 1.0493x over previous
//
#include <hip/hip_runtime.h>
#include <hip/hip_bf16.h>

// Problem constants
#define S_   3
#define B_   4096
#define DIN_ 1024
#define H1_  512
#define H2_  384
#define H3_  256
#define D_   128
#define K_   512
#define C_   3
#define INV_T 10.0f          // 1/TEMP
#define EPS_  1e-12f
#define EXP10 22026.465794806718f   // exp(1/T), diag(refl) analytically

typedef float f32x4 __attribute__((ext_vector_type(4)));
typedef short bf16x8 __attribute__((ext_vector_type(8)));

__device__ __forceinline__ unsigned short f2bf(float f) {
  unsigned int u = __float_as_uint(f);
  u = (u + 0x7FFF + ((u >> 16) & 1)) >> 16;   // round-to-nearest-even
  return (unsigned short)u;
}

// ---------------- reduction helpers ----------------
__device__ __forceinline__ float waveReduceSum(float v) {
#pragma unroll
  for (int off = 32; off > 0; off >>= 1) v += __shfl_down(v, off, 64);
  return v;
}

__device__ __forceinline__ float waveXorSum(float v) {
#pragma unroll
  for (int off = 32; off > 0; off >>= 1) v += __shfl_xor(v, off, 64);
  return v;
}

__device__ __forceinline__ float blockReduceSum128(float v, float* sbuf) {
  v = waveReduceSum(v);
  if ((threadIdx.x & 63) == 0) sbuf[threadIdx.x >> 6] = v;
  __syncthreads();
  float r = sbuf[0] + sbuf[1];
  __syncthreads();
  return r;
}

// ---------------- fp32 -> bf16 elementwise (n % 1024 == 0) ----------------
__global__ __launch_bounds__(256) void cvt_bf16_kernel(const float* __restrict__ in,
                                                       unsigned short* __restrict__ out,
                                                       int n) {
  int i = (blockIdx.x * 256 + threadIdx.x) * 4;
  if (i < n) {
    float4 v = *(const float4*)(in + i);
    out[i + 0] = f2bf(v.x); out[i + 1] = f2bf(v.y);
    out[i + 2] = f2bf(v.z); out[i + 3] = f2bf(v.w);
  }
}

// ---------------- W[S][K][N] fp32 -> Wt[S][N][K] bf16 ------
__global__ __launch_bounds__(256) void transpose_w_kernel(const float* __restrict__ W,
                                                          unsigned short* __restrict__ Wt,
                                                          int K, int N) {
  const int s = blockIdx.z;
  const int k0 = blockIdx.x * 32, n0 = blockIdx.y * 32;
  const int tx = threadIdx.x, ty = threadIdx.y;
  __shared__ float t[32][33];
  const float* Ws = W + (size_t)s * K * N;
  unsigned short* Wts = Wt + (size_t)s * N * K;
#pragma unroll
  for (int i = 0; i < 4; i++)
    t[ty + 8 * i][tx] = Ws[(size_t)(k0 + ty + 8 * i) * N + n0 + tx];
  __syncthreads();
#pragma unroll
  for (int i = 0; i < 4; i++)
    Wts[(size_t)(n0 + ty + 8 * i) * K + k0 + tx] = f2bf(t[tx][ty + 8 * i]);
}

// ---------------- LDS-staged MFMA GEMM, BK=64, register-pipelined ----------------
__global__ __launch_bounds__(256) void gemm_lds_kernel(
    const unsigned short* __restrict__ A, const unsigned short* __restrict__ Wt,
    const float* __restrict__ bias, void* __restrict__ Y,
    int K, int N, int relu, int out_f32) {
  const int t = threadIdx.x;
  const int lane = t & 63;
  const int w = t >> 6;
  const int ln = lane & 15, q = lane >> 4;
  const int wm = w >> 1, wn = w & 1;
  const int n0 = blockIdx.x * 128;
  const int mblk = blockIdx.y;
  const int s = mblk >> 6;                  // 4096/64 = 64 m-blocks per source
  const int m0 = mblk * 64;

  const unsigned short* Ag = A + (size_t)m0 * K;
  const unsigned short* Bg = Wt + (size_t)s * N * K + (size_t)n0 * K;
  const float* bs = bias + (size_t)s * N;

  __shared__ unsigned short Asm[2 * 64 * 32];
  __shared__ unsigned short Bsm[2 * 128 * 32];

  const int arow0 = t >> 3, ak8 = t & 7;
  const int aL0 = (ak8 >> 2) * 2048 + arow0 * 32 + (ak8 & 3) * 8;
  const int bL0 = (ak8 >> 2) * 4096 + arow0 * 32 + (ak8 & 3) * 8;
  const size_t gA0 = (size_t)arow0 * K + ak8 * 8;

  bf16x8 ra0 = *(const bf16x8*)(Ag + gA0);
  bf16x8 ra1 = *(const bf16x8*)(Ag + gA0 + (size_t)32 * K);
  bf16x8 rb0 = *(const bf16x8*)(Bg + gA0);
  bf16x8 rb1 = *(const bf16x8*)(Bg + gA0 + (size_t)32 * K);
  bf16x8 rb2 = *(const bf16x8*)(Bg + gA0 + (size_t)64 * K);
  bf16x8 rb3 = *(const bf16x8*)(Bg + gA0 + (size_t)96 * K);

  f32x4 acc[2][4];
#pragma unroll
  for (int i = 0; i < 2; i++)
#pragma unroll
    for (int j = 0; j < 4; j++) acc[i][j] = (f32x4){0.f, 0.f, 0.f, 0.f};

  for (int k0 = 0; k0 < K; k0 += 64) {
    *(bf16x8*)&Asm[aL0] = ra0;
    *(bf16x8*)&Asm[aL0 + 1024] = ra1;
    *(bf16x8*)&Bsm[bL0] = rb0;
    *(bf16x8*)&Bsm[bL0 + 1024] = rb1;
    *(bf16x8*)&Bsm[bL0 + 2048] = rb2;
    *(bf16x8*)&Bsm[bL0 + 3072] = rb3;
    __syncthreads();
    if (k0 + 64 < K) {
      const size_t g = gA0 + k0 + 64;
      ra0 = *(const bf16x8*)(Ag + g);
      ra1 = *(const bf16x8*)(Ag + g + (size_t)32 * K);
      rb0 = *(const bf16x8*)(Bg + g);
      rb1 = *(const bf16x8*)(Bg + g + (size_t)32 * K);
      rb2 = *(const bf16x8*)(Bg + g + (size_t)64 * K);
      rb3 = *(const bf16x8*)(Bg + g + (size_t)96 * K);
    }
    bf16x8 af[2][2], bf[4][2];
#pragma unroll
    for (int ti = 0; ti < 2; ti++)
#pragma unroll
      for (int ksl = 0; ksl < 2; ksl++)
        af[ti][ksl] = *(const bf16x8*)&Asm[ksl * 2048 + (wm * 32 + ti * 16 + ln) * 32 + q * 8];
#pragma unroll
    for (int tj = 0; tj < 4; tj++)
#pragma unroll
      for (int ksl = 0; ksl < 2; ksl++)
        bf[tj][ksl] = *(const bf16x8*)&Bsm[ksl * 4096 + (wn * 64 + tj * 16 + ln) * 32 + q * 8];
#pragma unroll
    for (int ksl = 0; ksl < 2; ksl++)
#pragma unroll
      for (int ti = 0; ti < 2; ti++)
#pragma unroll
        for (int tj = 0; tj < 4; tj++)
          acc[ti][tj] = __builtin_amdgcn_mfma_f32_16x16x32_bf16(af[ti][ksl], bf[tj][ksl], acc[ti][tj], 0, 0, 0);
    __syncthreads();
  }

#pragma unroll
  for (int ti = 0; ti < 2; ti++)
#pragma unroll
    for (int tj = 0; tj < 4; tj++) {
      const int cc = n0 + wn * 64 + tj * 16 + ln;
      const float bv = bs[cc];
#pragma unroll
      for (int reg = 0; reg < 4; reg++) {
        const int r = m0 + wm * 32 + ti * 16 + q * 4 + reg;
        float v = acc[ti][tj][reg] + bv;
        if (relu) v = fmaxf(v, 0.0f);
        if (out_f32) ((float*)Y)[(size_t)r * N + cc] = v;
        else ((unsigned short*)Y)[(size_t)r * N + cc] = f2bf(v);
      }
    }
}

// ---------------- fused attention score + softmax + fuse (4 b per block) --------
__global__ __launch_bounds__(256) void score_fuse_kernel(
    const float* __restrict__ emb, const float* __restrict__ qw1,
    const float* __restrict__ qb1, const float* __restrict__ qw2,
    float* __restrict__ fused) {
  const int b0 = blockIdx.x * 4;
  const int t = threadIdx.x;
  const int g = t >> 7, d = t & 127;     // half g handles rows 6g..6g+5
  __shared__ float e[12][D_];            // row r = s*4 + bi
  __shared__ float red[4][6];
  __shared__ float sc[12];
#pragma unroll
  for (int i = 0; i < 3; i++) {
    int idx = i * 512 + t * 2;
    int r = idx >> 7, dd = idx & 127;
    int s = r >> 2, bi = r & 3;
    *(float2*)&e[r][dd] = *(const float2*)(emb + ((size_t)(s * B_ + b0 + bi)) * D_ + dd);
  }
  __syncthreads();
  float acc[6] = {0.f, 0.f, 0.f, 0.f, 0.f, 0.f};
  for (int i = 0; i < D_; i++) {
    float w = qw1[i * D_ + d];
#pragma unroll
    for (int j = 0; j < 6; j++) acc[j] = fmaf(e[g * 6 + j][i], w, acc[j]);
  }
  const float qb = qb1[d], q2 = qw2[d];
  float val[6];
#pragma unroll
  for (int j = 0; j < 6; j++) val[j] = tanhf(acc[j] + qb) * q2;
  const int wave = t >> 6;
#pragma unroll
  for (int j = 0; j < 6; j++) {
    float v = waveReduceSum(val[j]);
    if ((t & 63) == 0) red[wave][j] = v;
  }
  __syncthreads();
  if (t < 12) {
    int gg = t / 6, j = t % 6;
    sc[gg * 6 + j] = red[2 * gg][j] + red[2 * gg + 1][j];
  }
  __syncthreads();
  // softmax over s + weighted sum, all from LDS
#pragma unroll
  for (int p = 0; p < 2; p++) {
    int idx = p * 256 + t;
    int bi = idx >> 7, dd = idx & 127;
    float s0 = sc[bi], s1 = sc[4 + bi], s2 = sc[8 + bi];
    float mx = fmaxf(s0, fmaxf(s1, s2));
    float e0 = __expf(s0 - mx), e1 = __expf(s1 - mx), e2 = __expf(s2 - mx);
    float inv = 1.0f / (e0 + e1 + e2);
    fused[(size_t)(b0 + bi) * D_ + dd] =
        (e0 * e[bi][dd] + e1 * e[4 + bi][dd] + e2 * e[8 + bi][dd]) * inv;
  }
}

// ---------------- fused codebook norms + normalized column-sum partials ---------
// grid C_*8; block 512 (8 waves). Phase 1: wave w computes n2 for rows w*8..w*8+7
// (writes cbn2 global for vq, 1/norm to LDS). Phase 2: threads 0..127 accumulate
// cb*inv over the 64 k's -> per-block partial (no atomics).
__global__ __launch_bounds__(512) void cbns_kernel(const float* __restrict__ cb,
                                                   float* __restrict__ cbn2,
                                                   float* __restrict__ cbsumP) {
  const int m = blockIdx.x >> 3;
  const int k0 = (blockIdx.x & 7) * 64;
  const int t = threadIdx.x, w = t >> 6, lane = t & 63;
  __shared__ float invn[64];
#pragma unroll
  for (int r = w * 8; r < w * 8 + 8; r++) {
    int k = k0 + r;
    float2 v = *(const float2*)(cb + ((size_t)m * K_ + k) * D_ + lane * 2);
    float n2 = waveXorSum(v.x * v.x + v.y * v.y);
    if (lane == 0) {
      cbn2[m * K_ + k] = n2;
      invn[r] = 1.0f / fmaxf(sqrtf(n2), EPS_);
    }
  }
  __syncthreads();
  if (t < D_) {
    float acc = 0.0f;
    for (int r = 0; r < 64; r++)
      acc += cb[((size_t)m * K_ + k0 + r) * D_ + t] * invn[r];
    cbsumP[(size_t)blockIdx.x * D_ + t] = acc;
  }
}

// ---------------- residual VQ: MFMA distance GEMM ----------------
__global__ __launch_bounds__(512) void vq_mfma_kernel(
    const float* __restrict__ fused, const float* __restrict__ cb,
    const unsigned short* __restrict__ cbb, const float* __restrict__ cbn2,
    float* __restrict__ qsum) {
  const int r0 = blockIdx.x * 16;
  const int t = threadIdx.x;
  const int w = t >> 6, lane = t & 63;
  const int ln = lane & 15, q = lane >> 4;
  __shared__ float resv[16][D_];
  __shared__ unsigned short resb[16][D_];
  __shared__ float candd[8][16];
  __shared__ int candk[8][16];
  __shared__ int bestk[16];

  {
    int idx = t * 4;
    int r = idx >> 7, dd = idx & 127;
    float4 v = *(const float4*)(fused + (size_t)(r0 + r) * D_ + dd);
    *(float4*)&resv[r][dd] = v;
    resb[r][dd + 0] = f2bf(v.x); resb[r][dd + 1] = f2bf(v.y);
    resb[r][dd + 2] = f2bf(v.z); resb[r][dd + 3] = f2bf(v.w);
  }
  __syncthreads();

  for (int c = 0; c < C_; c++) {
    bf16x8 a[4];
#pragma unroll
    for (int ks = 0; ks < 4; ks++)
      a[ks] = *(const bf16x8*)&resb[ln][ks * 32 + q * 8];
    f32x4 acc[4];
#pragma unroll
    for (int tt = 0; tt < 4; tt++) acc[tt] = (f32x4){0.f, 0.f, 0.f, 0.f};
#pragma unroll
    for (int tt = 0; tt < 4; tt++) {
      const int n = w * 64 + tt * 16 + ln;
      const unsigned short* bp = cbb + ((size_t)c * K_ + n) * D_;
#pragma unroll
      for (int ks = 0; ks < 4; ks++) {
        bf16x8 b = *(const bf16x8*)(bp + ks * 32 + q * 8);
        acc[tt] = __builtin_amdgcn_mfma_f32_16x16x32_bf16(a[ks], b, acc[tt], 0, 0, 0);
      }
    }
    float bd[4]; int bk[4];
#pragma unroll
    for (int reg = 0; reg < 4; reg++) { bd[reg] = 3.4e38f; bk[reg] = 0x7fffffff; }
#pragma unroll
    for (int tt = 0; tt < 4; tt++) {
      const int col = w * 64 + tt * 16 + ln;
      const float n2 = cbn2[c * K_ + col];
#pragma unroll
      for (int reg = 0; reg < 4; reg++) {
        float dist = n2 - 2.0f * acc[tt][reg];
        if (dist < bd[reg] || (dist == bd[reg] && col < bk[reg])) { bd[reg] = dist; bk[reg] = col; }
      }
    }
#pragma unroll
    for (int reg = 0; reg < 4; reg++) {
#pragma unroll
      for (int off = 8; off > 0; off >>= 1) {
        float d1 = __shfl_down(bd[reg], off, 16);
        int k1 = __shfl_down(bk[reg], off, 16);
        if (d1 < bd[reg] || (d1 == bd[reg] && k1 < bk[reg])) { bd[reg] = d1; bk[reg] = k1; }
      }
      if (ln == 0) { candd[w][q * 4 + reg] = bd[reg]; candk[w][q * 4 + reg] = bk[reg]; }
    }
    __syncthreads();
    if (w == 0) {
      int row = lane >> 2, g = lane & 3;
      float d0 = candd[2 * g][row]; int k0 = candk[2 * g][row];
      float d1 = candd[2 * g + 1][row]; int k1 = candk[2 * g + 1][row];
      if (d1 < d0 || (d1 == d0 && k1 < k0)) { d0 = d1; k0 = k1; }
#pragma unroll
      for (int off = 2; off > 0; off >>= 1) {
        float dn = __shfl_down(d0, off, 4);
        int kn = __shfl_down(k0, off, 4);
        if (dn < d0 || (dn == d0 && kn < k0)) { d0 = dn; k0 = kn; }
      }
      if (g == 0) bestk[row] = k0;
    }
    __syncthreads();
    {
      int idx = t * 4;
      int r = idx >> 7, dd = idx & 127;
      const float4 qv = *(const float4*)(cb + ((size_t)c * K_ + bestk[r]) * D_ + dd);
      float4 rv = *(float4*)&resv[r][dd];
      rv.x -= qv.x; rv.y -= qv.y; rv.z -= qv.z; rv.w -= qv.w;
      *(float4*)&resv[r][dd] = rv;
      resb[r][dd + 0] = f2bf(rv.x); resb[r][dd + 1] = f2bf(rv.y);
      resb[r][dd + 2] = f2bf(rv.z); resb[r][dd + 3] = f2bf(rv.w);
    }
    __syncthreads();
  }

  {
    int idx = t * 4;
    int r = idx >> 7, dd = idx & 127;
    float4 f = *(const float4*)(fused + (size_t)(r0 + r) * D_ + dd);
    float4 rv = *(float4*)&resv[r][dd];
    f.x -= rv.x; f.y -= rv.y; f.z -= rv.z; f.w -= rv.w;
    *(float4*)(qsum + (size_t)(r0 + r) * D_ + dd) = f;
  }
}

// ---------------- fused normalize + pos: block per b, wave per row ----------------
// wave 0: qsum[b] -> z1; waves 1..3: emb[s][b] -> z2s. Writes bf16 zb only
// (fp32 z eliminated); pos[s][b] computed in-block from LDS.
__global__ __launch_bounds__(256) void normpos_kernel(
    const float* __restrict__ qsum, const float* __restrict__ emb,
    unsigned short* __restrict__ zb, float* __restrict__ pos) {
  const int b = blockIdx.x;
  const int w = threadIdx.x >> 6, lane = threadIdx.x & 63;
  __shared__ float zl[4][D_];
  const float* src = (w == 0) ? (qsum + (size_t)b * D_)
                              : (emb + (size_t)((w - 1) * B_ + b) * D_);
  float2 v = *(const float2*)(src + lane * 2);
  float n2 = waveXorSum(v.x * v.x + v.y * v.y);
  float inv = 1.0f / fmaxf(sqrtf(n2), EPS_);
  float zx = v.x * inv, zy = v.y * inv;
  const size_t g = (size_t)w * B_ + b;
  zb[g * D_ + lane * 2 + 0] = f2bf(zx);
  zb[g * D_ + lane * 2 + 1] = f2bf(zy);
  zl[w][lane * 2] = zx; zl[w][lane * 2 + 1] = zy;
  __syncthreads();
  if (w >= 1) {
    float2 a = *(const float2*)&zl[0][lane * 2];
    float dsum = waveXorSum(a.x * zx + a.y * zy);
    if (lane == 0) pos[(w - 1) * B_ + b] = dsum;
  }
}

// ---------------- contrastive exp-rowsums: LDS-staged B tiles ----------------
__global__ __launch_bounds__(256) void contrast_mfma_kernel(
    const unsigned short* __restrict__ zb, float* __restrict__ rsP) {
  const int jc = blockIdx.x, ib = blockIdx.y, m = blockIdx.z;
  const int t = threadIdx.x;
  const int w = t >> 6, lane = t & 63;
  const int ln = lane & 15, q = lane >> 4;
  const int i0 = ib * 128 + w * 32;
  const unsigned short* Za = zb;
  const unsigned short* Zm = zb + (size_t)m * B_ * D_;

  __shared__ unsigned short Zsm[64 * 136];

  bf16x8 a[2][4];
#pragma unroll
  for (int si = 0; si < 2; si++)
#pragma unroll
    for (int ks = 0; ks < 4; ks++)
      a[si][ks] = *(const bf16x8*)(Za + (size_t)(i0 + si * 16 + ln) * D_ + ks * 32 + q * 8);

  const unsigned short* tb = Zm + (size_t)(jc * 1024) * D_;
  bf16x8 rz[4];
#pragma unroll
  for (int p = 0; p < 4; p++)
    rz[p] = *(const bf16x8*)(tb + t * 8 + p * 2048);

  float e[2][4] = {};
  for (int jt = 0; jt < 16; jt++) {
#pragma unroll
    for (int p = 0; p < 4; p++) {
      int c = t + p * 256;
      *(bf16x8*)&Zsm[(c >> 4) * 136 + (c & 15) * 8] = rz[p];
    }
    __syncthreads();
    if (jt + 1 < 16) {
      const unsigned short* tn = Zm + (size_t)(jc * 1024 + (jt + 1) * 64) * D_;
#pragma unroll
      for (int p = 0; p < 4; p++)
        rz[p] = *(const bf16x8*)(tn + t * 8 + p * 2048);
    }
    f32x4 acc[2][4];
#pragma unroll
    for (int si = 0; si < 2; si++)
#pragma unroll
      for (int tj = 0; tj < 4; tj++) acc[si][tj] = (f32x4){0.f, 0.f, 0.f, 0.f};
#pragma unroll
    for (int tj = 0; tj < 4; tj++) {
      bf16x8 b[4];
#pragma unroll
      for (int ks = 0; ks < 4; ks++)
        b[ks] = *(const bf16x8*)&Zsm[(tj * 16 + ln) * 136 + ks * 32 + q * 8];
#pragma unroll
      for (int ks = 0; ks < 4; ks++) {
        acc[0][tj] = __builtin_amdgcn_mfma_f32_16x16x32_bf16(a[0][ks], b[ks], acc[0][tj], 0, 0, 0);
        acc[1][tj] = __builtin_amdgcn_mfma_f32_16x16x32_bf16(a[1][ks], b[ks], acc[1][tj], 0, 0, 0);
      }
    }
#pragma unroll
    for (int si = 0; si < 2; si++)
#pragma unroll
      for (int reg = 0; reg < 4; reg++) {
        float s = 0.f;
#pragma unroll
        for (int tj = 0; tj < 4; tj++) s += __expf(acc[si][tj][reg] * INV_T);
        e[si][reg] += s;
      }
    __syncthreads();
  }
#pragma unroll
  for (int si = 0; si < 2; si++)
#pragma unroll
    for (int reg = 0; reg < 4; reg++) {
#pragma unroll
      for (int off = 8; off > 0; off >>= 1)
        e[si][reg] += __shfl_xor(e[si][reg], off, 16);
    }
  if (ln == 0) {
#pragma unroll
    for (int si = 0; si < 2; si++)
#pragma unroll
      for (int reg = 0; reg < 4; reg++)
        rsP[((size_t)m * 4 + jc) * B_ + i0 + si * 16 + q * 4 + reg] = e[si][reg];
  }
}

// ---------------- per-source loss reduce -> per-block partials ----------------
__global__ __launch_bounds__(256) void lossred_kernel(const float* __restrict__ rsP,
                                                      const float* __restrict__ pos,
                                                      float* __restrict__ lossP) {
  const int s = blockIdx.y;
  const int i = blockIdx.x * 256 + threadIdx.x;
  __shared__ float red[4];
  float denom = -EXP10;
#pragma unroll
  for (int jc = 0; jc < 4; jc++) {
    denom += rsP[(size_t)jc * B_ + i];                      // m = 0 (refl)
    denom += rsP[((size_t)(1 + s) * 4 + jc) * B_ + i];      // m = 1+s
  }
  float val = logf(denom) - pos[s * B_ + i] * INV_T;
  float v = waveReduceSum(val);
  if ((threadIdx.x & 63) == 0) red[threadIdx.x >> 6] = v;
  __syncthreads();
  if (threadIdx.x == 0)
    lossP[s * 16 + blockIdx.x] = red[0] + red[1] + red[2] + red[3];
}

// ---------------- finalize: sum partials + outputs ----------------
__global__ __launch_bounds__(128) void finalize_kernel(const float* __restrict__ cbsumP,
                                                       const float* __restrict__ lossP,
                                                       float* __restrict__ out) {
  const int d = threadIdx.x;
  __shared__ float red[2];
  float acc = 0.0f;
#pragma unroll
  for (int m = 0; m < C_; m++) {
    float v = 0.0f;
#pragma unroll
    for (int blk = 0; blk < 8; blk++) v += cbsumP[(size_t)(m * 8 + blk) * D_ + d];
    acc += v * v;
  }
  float tot = blockReduceSum128(acc, red);
  if (d == 0) out[0] = tot * (1.0f / (3.0f * 512.0f * 512.0f));
  if (d == 1) out[1] = 0.0f;
  if (d >= 2 && d < 5) {
    float l = 0.0f;
#pragma unroll
    for (int x = 0; x < 16; x++) l += lossP[(d - 2) * 16 + x];
    out[d] = l * (1.0f / 4096.0f);
  }
}

extern "C" void kernel_launch(void* const* d_in, const int* in_sizes, int n_in,
                              void* d_out, int out_size, void* d_ws, size_t ws_size,
                              hipStream_t stream) {
  const float* x    = (const float*)d_in[0];
  const float* w1   = (const float*)d_in[1];
  const float* b1   = (const float*)d_in[2];
  const float* w2   = (const float*)d_in[3];
  const float* b2   = (const float*)d_in[4];
  const float* w3   = (const float*)d_in[5];
  const float* b3   = (const float*)d_in[6];
  const float* w4   = (const float*)d_in[7];
  const float* b4   = (const float*)d_in[8];
  const float* qw1  = (const float*)d_in[9];
  const float* qb1  = (const float*)d_in[10];
  const float* qw2  = (const float*)d_in[11];
  const float* cb   = (const float*)d_in[12];
  float* out = (float*)d_out;
  char* base = (char*)d_ws;

  size_t o = 0;
  auto alloc = [&](size_t bytes) { size_t r = o; o += (bytes + 255) & ~(size_t)255; return r; };
  size_t o_xb   = alloc((size_t)S_ * B_ * DIN_ * 2);
  size_t o_wt1  = alloc((size_t)S_ * H1_ * DIN_ * 2);
  size_t o_wt2  = alloc((size_t)S_ * H2_ * H1_ * 2);
  size_t o_wt3  = alloc((size_t)S_ * H3_ * H2_ * 2);
  size_t o_wt4  = alloc((size_t)S_ * D_ * H3_ * 2);
  size_t o_h1b  = alloc((size_t)S_ * B_ * H1_ * 2);
  size_t o_h2b  = alloc((size_t)S_ * B_ * H2_ * 2);
  size_t o_h3b  = alloc((size_t)S_ * B_ * H3_ * 2);
  size_t o_emb  = alloc((size_t)S_ * B_ * D_ * 4);
  size_t o_fus  = alloc((size_t)B_ * D_ * 4);
  size_t o_qs   = alloc((size_t)B_ * D_ * 4);
  size_t o_zb   = alloc((size_t)4 * B_ * D_ * 2);
  size_t o_cbn2 = alloc((size_t)C_ * K_ * 4);
  size_t o_cbb  = alloc((size_t)C_ * K_ * D_ * 2);
  size_t o_rsP  = alloc((size_t)4 * 4 * B_ * 4);
  size_t o_cbsP = alloc((size_t)C_ * 8 * D_ * 4);
  size_t o_lossP= alloc((size_t)S_ * 16 * 4);
  size_t o_pos  = alloc((size_t)S_ * B_ * 4);
  (void)ws_size; (void)in_sizes; (void)n_in; (void)out_size;

  unsigned short* xb  = (unsigned short*)(base + o_xb);
  unsigned short* wt1 = (unsigned short*)(base + o_wt1);
  unsigned short* wt2 = (unsigned short*)(base + o_wt2);
  unsigned short* wt3 = (unsigned short*)(base + o_wt3);
  unsigned short* wt4 = (unsigned short*)(base + o_wt4);
  unsigned short* h1b = (unsigned short*)(base + o_h1b);
  unsigned short* h2b = (unsigned short*)(base + o_h2b);
  unsigned short* h3b = (unsigned short*)(base + o_h3b);
  float* emb   = (float*)(base + o_emb);
  float* fused = (float*)(base + o_fus);
  float* qsum  = (float*)(base + o_qs);
  unsigned short* zb = (unsigned short*)(base + o_zb);
  float* cbn2  = (float*)(base + o_cbn2);
  unsigned short* cbb = (unsigned short*)(base + o_cbb);
  float* rsP   = (float*)(base + o_rsP);
  float* cbsumP= (float*)(base + o_cbsP);
  float* lossP = (float*)(base + o_lossP);
  float* pos   = (float*)(base + o_pos);

  // input + weight conversion
  cvt_bf16_kernel<<<dim3((S_ * B_ * DIN_) / 1024), 256, 0, stream>>>(x, xb, S_ * B_ * DIN_);
  cvt_bf16_kernel<<<dim3((C_ * K_ * D_) / 1024), 256, 0, stream>>>(cb, cbb, C_ * K_ * D_);
  transpose_w_kernel<<<dim3(DIN_ / 32, H1_ / 32, S_), dim3(32, 8), 0, stream>>>(w1, wt1, DIN_, H1_);
  transpose_w_kernel<<<dim3(H1_ / 32, H2_ / 32, S_), dim3(32, 8), 0, stream>>>(w2, wt2, H1_, H2_);
  transpose_w_kernel<<<dim3(H2_ / 32, H3_ / 32, S_), dim3(32, 8), 0, stream>>>(w3, wt3, H2_, H3_);
  transpose_w_kernel<<<dim3(H3_ / 32, D_ / 32, S_), dim3(32, 8), 0, stream>>>(w4, wt4, H3_, D_);

  // codebook norms + cbsum partials (before vq; produces cbn2)
  cbns_kernel<<<dim3(C_ * 8), 512, 0, stream>>>(cb, cbn2, cbsumP);

  // encoder MLP via LDS-staged MFMA (BK=64)
  const int Mtot = S_ * B_;
  gemm_lds_kernel<<<dim3(H1_ / 128, Mtot / 64), 256, 0, stream>>>(xb, wt1, b1, h1b, DIN_, H1_, 1, 0);
  gemm_lds_kernel<<<dim3(H2_ / 128, Mtot / 64), 256, 0, stream>>>(h1b, wt2, b2, h2b, H1_, H2_, 1, 0);
  gemm_lds_kernel<<<dim3(H3_ / 128, Mtot / 64), 256, 0, stream>>>(h2b, wt3, b3, h3b, H2_, H3_, 1, 0);
  gemm_lds_kernel<<<dim3(D_ / 128, Mtot / 64), 256, 0, stream>>>(h3b, wt4, b4, emb, H3_, D_, 0, 1);

  // fused attention score + softmax + fuse
  score_fuse_kernel<<<dim3(B_ / 4), 256, 0, stream>>>(emb, qw1, qb1, qw2, fused);

  // residual VQ (MFMA distance GEMM)
  vq_mfma_kernel<<<dim3(B_ / 16), 512, 0, stream>>>(fused, cb, cbb, cbn2, qsum);

  // fused normalize + pos (writes bf16 zb + pos)
  normpos_kernel<<<dim3(B_), 256, 0, stream>>>(qsum, emb, zb, pos);

  // contrastive rowsum partials
  contrast_mfma_kernel<<<dim3(4, 32, 4), 256, 0, stream>>>(zb, rsP);

  // per-source contrastive partials
  lossred_kernel<<<dim3(B_ / 256, S_), 256, 0, stream>>>(rsP, pos, lossP);

  finalize_kernel<<<dim3(1), 128, 0, stream>>>(cbsumP, lossP, out);
}

// Round 12
// 252.640 us; speedup vs baseline: 1.2487x; 1.0207x over previous
//
#include <hip/hip_runtime.h>
#include <hip/hip_bf16.h>

// Problem constants
#define S_   3
#define B_   4096
#define DIN_ 1024
#define H1_  512
#define H2_  384
#define H3_  256
#define D_   128
#define K_   512
#define C_   3
#define INV_T 10.0f          // 1/TEMP
#define EPS_  1e-12f
#define EXP10 22026.465794806718f   // exp(1/T), diag(refl) analytically

typedef float f32x4 __attribute__((ext_vector_type(4)));
typedef short bf16x8 __attribute__((ext_vector_type(8)));

__device__ __forceinline__ unsigned short f2bf(float f) {
  unsigned int u = __float_as_uint(f);
  u = (u + 0x7FFF + ((u >> 16) & 1)) >> 16;   // round-to-nearest-even
  return (unsigned short)u;
}

// ---------------- reduction helpers ----------------
__device__ __forceinline__ float waveReduceSum(float v) {
#pragma unroll
  for (int off = 32; off > 0; off >>= 1) v += __shfl_down(v, off, 64);
  return v;
}

__device__ __forceinline__ float waveXorSum(float v) {
#pragma unroll
  for (int off = 32; off > 0; off >>= 1) v += __shfl_xor(v, off, 64);
  return v;
}

__device__ __forceinline__ float blockReduceSum128(float v, float* sbuf) {
  v = waveReduceSum(v);
  if ((threadIdx.x & 63) == 0) sbuf[threadIdx.x >> 6] = v;
  __syncthreads();
  float r = sbuf[0] + sbuf[1];
  __syncthreads();
  return r;
}

// ---------------- fp32 -> bf16 elementwise (n % 1024 == 0) ----------------
__global__ __launch_bounds__(256) void cvt_bf16_kernel(const float* __restrict__ in,
                                                       unsigned short* __restrict__ out,
                                                       int n) {
  int i = (blockIdx.x * 256 + threadIdx.x) * 4;
  if (i < n) {
    float4 v = *(const float4*)(in + i);
    out[i + 0] = f2bf(v.x); out[i + 1] = f2bf(v.y);
    out[i + 2] = f2bf(v.z); out[i + 3] = f2bf(v.w);
  }
}

// ---------------- W[S][K][N] fp32 -> swizzled bf16 Wsw ----------------
// Wsw layout = gemm LDS-chunk order: per (s, n-block of 128, k-tile of 64):
// 8192 shorts; element (n,k): ksl=(k>>5)&1, row=n&127, col8k=(k&31);
// offset = tile*8192 + ksl*4096 + row*32 + (k&31).
__global__ __launch_bounds__(256) void transpose_w_kernel(const float* __restrict__ W,
                                                          unsigned short* __restrict__ Wsw,
                                                          int K, int N) {
  const int s = blockIdx.z;
  const int k0 = blockIdx.x * 32, n0 = blockIdx.y * 32;
  const int tx = threadIdx.x, ty = threadIdx.y;
  __shared__ float tt[32][33];
  const float* Ws = W + (size_t)s * K * N;
  const int nb = N >> 7, kb = K >> 6;
#pragma unroll
  for (int i = 0; i < 4; i++)
    tt[ty + 8 * i][tx] = Ws[(size_t)(k0 + ty + 8 * i) * N + n0 + tx];
  __syncthreads();
  const int k = k0 + tx;            // fixed ksl/kt within this 32-span
  const int kt = k >> 6, ksl = (k >> 5) & 1;
#pragma unroll
  for (int i = 0; i < 4; i++) {
    int n = n0 + ty + 8 * i;
    size_t dst = ((size_t)(s * nb + (n >> 7)) * kb + kt) * 8192 +
                 (size_t)ksl * 4096 + (size_t)(n & 127) * 32 + (k & 31);
    Wsw[dst] = f2bf(tt[tx][ty + 8 * i]);
  }
}

// ---------------- LDS-staged MFMA GEMM, BK=64, swizzled weights ----------------
// B staging now reads Wsw as contiguous (p*256+t)*16B streams (fully coalesced)
// and stores LDS at chunk*16B (contiguous). A staging unchanged.
__global__ __launch_bounds__(256) void gemm_lds_kernel(
    const unsigned short* __restrict__ A, const unsigned short* __restrict__ Wsw,
    const float* __restrict__ bias, void* __restrict__ Y,
    int K, int N, int relu, int out_f32) {
  const int t = threadIdx.x;
  const int lane = t & 63;
  const int w = t >> 6;
  const int ln = lane & 15, q = lane >> 4;
  const int wm = w >> 1, wn = w & 1;
  const int n0 = blockIdx.x * 128;
  const int mblk = blockIdx.y;
  const int s = mblk >> 6;                  // 4096/64 = 64 m-blocks per source
  const int m0 = mblk * 64;
  const int nb = N >> 7, kb = K >> 6;

  const unsigned short* Ag = A + (size_t)m0 * K;
  const unsigned short* Bt = Wsw + ((size_t)(s * nb + blockIdx.x) * kb) * 8192;
  const float* bs = bias + (size_t)s * N;

  __shared__ unsigned short Asm[2 * 64 * 32];
  __shared__ unsigned short Bsm[2 * 128 * 32];

  const int arow0 = t >> 3, ak8 = t & 7;
  const int aL0 = (ak8 >> 2) * 2048 + arow0 * 32 + (ak8 & 3) * 8;
  const size_t gA0 = (size_t)arow0 * K + ak8 * 8;

  bf16x8 ra0 = *(const bf16x8*)(Ag + gA0);
  bf16x8 ra1 = *(const bf16x8*)(Ag + gA0 + (size_t)32 * K);
  bf16x8 rb[4];
#pragma unroll
  for (int p = 0; p < 4; p++)
    rb[p] = *(const bf16x8*)(Bt + (size_t)(p * 256 + t) * 8);

  f32x4 acc[2][4];
#pragma unroll
  for (int i = 0; i < 2; i++)
#pragma unroll
    for (int j = 0; j < 4; j++) acc[i][j] = (f32x4){0.f, 0.f, 0.f, 0.f};

  for (int kt = 0; kt < kb; kt++) {
    *(bf16x8*)&Asm[aL0] = ra0;
    *(bf16x8*)&Asm[aL0 + 1024] = ra1;
#pragma unroll
    for (int p = 0; p < 4; p++)
      *(bf16x8*)&Bsm[(size_t)(p * 256 + t) * 8] = rb[p];
    __syncthreads();
    if (kt + 1 < kb) {
      const size_t g = gA0 + (size_t)(kt + 1) * 64;
      ra0 = *(const bf16x8*)(Ag + g);
      ra1 = *(const bf16x8*)(Ag + g + (size_t)32 * K);
      const unsigned short* Bn = Bt + (size_t)(kt + 1) * 8192;
#pragma unroll
      for (int p = 0; p < 4; p++)
        rb[p] = *(const bf16x8*)(Bn + (size_t)(p * 256 + t) * 8);
    }
    bf16x8 af[2][2], bf[4][2];
#pragma unroll
    for (int ti = 0; ti < 2; ti++)
#pragma unroll
      for (int ksl = 0; ksl < 2; ksl++)
        af[ti][ksl] = *(const bf16x8*)&Asm[ksl * 2048 + (wm * 32 + ti * 16 + ln) * 32 + q * 8];
#pragma unroll
    for (int tj = 0; tj < 4; tj++)
#pragma unroll
      for (int ksl = 0; ksl < 2; ksl++)
        bf[tj][ksl] = *(const bf16x8*)&Bsm[ksl * 4096 + (wn * 64 + tj * 16 + ln) * 32 + q * 8];
#pragma unroll
    for (int ksl = 0; ksl < 2; ksl++)
#pragma unroll
      for (int ti = 0; ti < 2; ti++)
#pragma unroll
        for (int tj = 0; tj < 4; tj++)
          acc[ti][tj] = __builtin_amdgcn_mfma_f32_16x16x32_bf16(af[ti][ksl], bf[tj][ksl], acc[ti][tj], 0, 0, 0);
    __syncthreads();
  }

#pragma unroll
  for (int ti = 0; ti < 2; ti++)
#pragma unroll
    for (int tj = 0; tj < 4; tj++) {
      const int cc = n0 + wn * 64 + tj * 16 + ln;
      const float bv = bs[cc];
#pragma unroll
      for (int reg = 0; reg < 4; reg++) {
        const int r = m0 + wm * 32 + ti * 16 + q * 4 + reg;
        float v = acc[ti][tj][reg] + bv;
        if (relu) v = fmaxf(v, 0.0f);
        if (out_f32) ((float*)Y)[(size_t)r * N + cc] = v;
        else ((unsigned short*)Y)[(size_t)r * N + cc] = f2bf(v);
      }
    }
}

// ---------------- fused attention score + softmax + fuse (4 b per block) --------
__global__ __launch_bounds__(256) void score_fuse_kernel(
    const float* __restrict__ emb, const float* __restrict__ qw1,
    const float* __restrict__ qb1, const float* __restrict__ qw2,
    float* __restrict__ fused) {
  const int b0 = blockIdx.x * 4;
  const int t = threadIdx.x;
  const int g = t >> 7, d = t & 127;
  __shared__ float e[12][D_];
  __shared__ float red[4][6];
  __shared__ float sc[12];
#pragma unroll
  for (int i = 0; i < 3; i++) {
    int idx = i * 512 + t * 2;
    int r = idx >> 7, dd = idx & 127;
    int s = r >> 2, bi = r & 3;
    *(float2*)&e[r][dd] = *(const float2*)(emb + ((size_t)(s * B_ + b0 + bi)) * D_ + dd);
  }
  __syncthreads();
  float acc[6] = {0.f, 0.f, 0.f, 0.f, 0.f, 0.f};
  for (int i = 0; i < D_; i++) {
    float w = qw1[i * D_ + d];
#pragma unroll
    for (int j = 0; j < 6; j++) acc[j] = fmaf(e[g * 6 + j][i], w, acc[j]);
  }
  const float qb = qb1[d], q2 = qw2[d];
  float val[6];
#pragma unroll
  for (int j = 0; j < 6; j++) val[j] = tanhf(acc[j] + qb) * q2;
  const int wave = t >> 6;
#pragma unroll
  for (int j = 0; j < 6; j++) {
    float v = waveReduceSum(val[j]);
    if ((t & 63) == 0) red[wave][j] = v;
  }
  __syncthreads();
  if (t < 12) {
    int gg = t / 6, j = t % 6;
    sc[gg * 6 + j] = red[2 * gg][j] + red[2 * gg + 1][j];
  }
  __syncthreads();
#pragma unroll
  for (int p = 0; p < 2; p++) {
    int idx = p * 256 + t;
    int bi = idx >> 7, dd = idx & 127;
    float s0 = sc[bi], s1 = sc[4 + bi], s2 = sc[8 + bi];
    float mx = fmaxf(s0, fmaxf(s1, s2));
    float e0 = __expf(s0 - mx), e1 = __expf(s1 - mx), e2 = __expf(s2 - mx);
    float inv = 1.0f / (e0 + e1 + e2);
    fused[(size_t)(b0 + bi) * D_ + dd] =
        (e0 * e[bi][dd] + e1 * e[4 + bi][dd] + e2 * e[8 + bi][dd]) * inv;
  }
}

// ---------------- fused codebook norms + bf16 convert + column-sum partials -----
__global__ __launch_bounds__(512) void cbns_kernel(const float* __restrict__ cb,
                                                   float* __restrict__ cbn2,
                                                   float* __restrict__ cbsumP,
                                                   unsigned short* __restrict__ cbb) {
  const int m = blockIdx.x >> 3;
  const int k0 = (blockIdx.x & 7) * 64;
  const int t = threadIdx.x, w = t >> 6, lane = t & 63;
  __shared__ float invn[64];
#pragma unroll
  for (int r = w * 8; r < w * 8 + 8; r++) {
    int k = k0 + r;
    float2 v = *(const float2*)(cb + ((size_t)m * K_ + k) * D_ + lane * 2);
    unsigned short* crow = cbb + ((size_t)m * K_ + k) * D_;
    crow[lane * 2 + 0] = f2bf(v.x);
    crow[lane * 2 + 1] = f2bf(v.y);
    float n2 = waveXorSum(v.x * v.x + v.y * v.y);
    if (lane == 0) {
      cbn2[m * K_ + k] = n2;
      invn[r] = 1.0f / fmaxf(sqrtf(n2), EPS_);
    }
  }
  __syncthreads();
  if (t < D_) {
    float acc = 0.0f;
    for (int r = 0; r < 64; r++)
      acc += cb[((size_t)m * K_ + k0 + r) * D_ + t] * invn[r];
    cbsumP[(size_t)blockIdx.x * D_ + t] = acc;
  }
}

// ---------------- residual VQ: MFMA distance GEMM ----------------
__global__ __launch_bounds__(512) void vq_mfma_kernel(
    const float* __restrict__ fused, const float* __restrict__ cb,
    const unsigned short* __restrict__ cbb, const float* __restrict__ cbn2,
    float* __restrict__ qsum) {
  const int r0 = blockIdx.x * 16;
  const int t = threadIdx.x;
  const int w = t >> 6, lane = t & 63;
  const int ln = lane & 15, q = lane >> 4;
  __shared__ float resv[16][D_];
  __shared__ unsigned short resb[16][D_];
  __shared__ float candd[8][16];
  __shared__ int candk[8][16];
  __shared__ int bestk[16];

  {
    int idx = t * 4;
    int r = idx >> 7, dd = idx & 127;
    float4 v = *(const float4*)(fused + (size_t)(r0 + r) * D_ + dd);
    *(float4*)&resv[r][dd] = v;
    resb[r][dd + 0] = f2bf(v.x); resb[r][dd + 1] = f2bf(v.y);
    resb[r][dd + 2] = f2bf(v.z); resb[r][dd + 3] = f2bf(v.w);
  }
  __syncthreads();

  for (int c = 0; c < C_; c++) {
    bf16x8 a[4];
#pragma unroll
    for (int ks = 0; ks < 4; ks++)
      a[ks] = *(const bf16x8*)&resb[ln][ks * 32 + q * 8];
    f32x4 acc[4];
#pragma unroll
    for (int tt = 0; tt < 4; tt++) acc[tt] = (f32x4){0.f, 0.f, 0.f, 0.f};
#pragma unroll
    for (int tt = 0; tt < 4; tt++) {
      const int n = w * 64 + tt * 16 + ln;
      const unsigned short* bp = cbb + ((size_t)c * K_ + n) * D_;
#pragma unroll
      for (int ks = 0; ks < 4; ks++) {
        bf16x8 b = *(const bf16x8*)(bp + ks * 32 + q * 8);
        acc[tt] = __builtin_amdgcn_mfma_f32_16x16x32_bf16(a[ks], b, acc[tt], 0, 0, 0);
      }
    }
    float bd[4]; int bk[4];
#pragma unroll
    for (int reg = 0; reg < 4; reg++) { bd[reg] = 3.4e38f; bk[reg] = 0x7fffffff; }
#pragma unroll
    for (int tt = 0; tt < 4; tt++) {
      const int col = w * 64 + tt * 16 + ln;
      const float n2 = cbn2[c * K_ + col];
#pragma unroll
      for (int reg = 0; reg < 4; reg++) {
        float dist = n2 - 2.0f * acc[tt][reg];
        if (dist < bd[reg] || (dist == bd[reg] && col < bk[reg])) { bd[reg] = dist; bk[reg] = col; }
      }
    }
#pragma unroll
    for (int reg = 0; reg < 4; reg++) {
#pragma unroll
      for (int off = 8; off > 0; off >>= 1) {
        float d1 = __shfl_down(bd[reg], off, 16);
        int k1 = __shfl_down(bk[reg], off, 16);
        if (d1 < bd[reg] || (d1 == bd[reg] && k1 < bk[reg])) { bd[reg] = d1; bk[reg] = k1; }
      }
      if (ln == 0) { candd[w][q * 4 + reg] = bd[reg]; candk[w][q * 4 + reg] = bk[reg]; }
    }
    __syncthreads();
    if (w == 0) {
      int row = lane >> 2, g = lane & 3;
      float d0 = candd[2 * g][row]; int k0 = candk[2 * g][row];
      float d1 = candd[2 * g + 1][row]; int k1 = candk[2 * g + 1][row];
      if (d1 < d0 || (d1 == d0 && k1 < k0)) { d0 = d1; k0 = k1; }
#pragma unroll
      for (int off = 2; off > 0; off >>= 1) {
        float dn = __shfl_down(d0, off, 4);
        int kn = __shfl_down(k0, off, 4);
        if (dn < d0 || (dn == d0 && kn < k0)) { d0 = dn; k0 = kn; }
      }
      if (g == 0) bestk[row] = k0;
    }
    __syncthreads();
    {
      int idx = t * 4;
      int r = idx >> 7, dd = idx & 127;
      const float4 qv = *(const float4*)(cb + ((size_t)c * K_ + bestk[r]) * D_ + dd);
      float4 rv = *(float4*)&resv[r][dd];
      rv.x -= qv.x; rv.y -= qv.y; rv.z -= qv.z; rv.w -= qv.w;
      *(float4*)&resv[r][dd] = rv;
      resb[r][dd + 0] = f2bf(rv.x); resb[r][dd + 1] = f2bf(rv.y);
      resb[r][dd + 2] = f2bf(rv.z); resb[r][dd + 3] = f2bf(rv.w);
    }
    __syncthreads();
  }

  {
    int idx = t * 4;
    int r = idx >> 7, dd = idx & 127;
    float4 f = *(const float4*)(fused + (size_t)(r0 + r) * D_ + dd);
    float4 rv = *(float4*)&resv[r][dd];
    f.x -= rv.x; f.y -= rv.y; f.z -= rv.z; f.w -= rv.w;
    *(float4*)(qsum + (size_t)(r0 + r) * D_ + dd) = f;
  }
}

// ---------------- fused normalize + pos: block per b, wave per row ----------------
__global__ __launch_bounds__(256) void normpos_kernel(
    const float* __restrict__ qsum, const float* __restrict__ emb,
    unsigned short* __restrict__ zb, float* __restrict__ pos) {
  const int b = blockIdx.x;
  const int w = threadIdx.x >> 6, lane = threadIdx.x & 63;
  __shared__ float zl[4][D_];
  const float* src = (w == 0) ? (qsum + (size_t)b * D_)
                              : (emb + (size_t)((w - 1) * B_ + b) * D_);
  float2 v = *(const float2*)(src + lane * 2);
  float n2 = waveXorSum(v.x * v.x + v.y * v.y);
  float inv = 1.0f / fmaxf(sqrtf(n2), EPS_);
  float zx = v.x * inv, zy = v.y * inv;
  const size_t g = (size_t)w * B_ + b;
  zb[g * D_ + lane * 2 + 0] = f2bf(zx);
  zb[g * D_ + lane * 2 + 1] = f2bf(zy);
  zl[w][lane * 2] = zx; zl[w][lane * 2 + 1] = zy;
  __syncthreads();
  if (w >= 1) {
    float2 a = *(const float2*)&zl[0][lane * 2];
    float dsum = waveXorSum(a.x * zx + a.y * zy);
    if (lane == 0) pos[(w - 1) * B_ + b] = dsum;
  }
}

// ---------------- contrastive exp-rowsums: LDS-staged B tiles ----------------
__global__ __launch_bounds__(256) void contrast_mfma_kernel(
    const unsigned short* __restrict__ zb, float* __restrict__ rsP) {
  const int jc = blockIdx.x, ib = blockIdx.y, m = blockIdx.z;
  const int t = threadIdx.x;
  const int w = t >> 6, lane = t & 63;
  const int ln = lane & 15, q = lane >> 4;
  const int i0 = ib * 128 + w * 32;
  const unsigned short* Za = zb;
  const unsigned short* Zm = zb + (size_t)m * B_ * D_;

  __shared__ unsigned short Zsm[64 * 136];

  bf16x8 a[2][4];
#pragma unroll
  for (int si = 0; si < 2; si++)
#pragma unroll
    for (int ks = 0; ks < 4; ks++)
      a[si][ks] = *(const bf16x8*)(Za + (size_t)(i0 + si * 16 + ln) * D_ + ks * 32 + q * 8);

  const unsigned short* tb = Zm + (size_t)(jc * 1024) * D_;
  bf16x8 rz[4];
#pragma unroll
  for (int p = 0; p < 4; p++)
    rz[p] = *(const bf16x8*)(tb + t * 8 + p * 2048);

  float e[2][4] = {};
  for (int jt = 0; jt < 16; jt++) {
#pragma unroll
    for (int p = 0; p < 4; p++) {
      int c = t + p * 256;
      *(bf16x8*)&Zsm[(c >> 4) * 136 + (c & 15) * 8] = rz[p];
    }
    __syncthreads();
    if (jt + 1 < 16) {
      const unsigned short* tn = Zm + (size_t)(jc * 1024 + (jt + 1) * 64) * D_;
#pragma unroll
      for (int p = 0; p < 4; p++)
        rz[p] = *(const bf16x8*)(tn + t * 8 + p * 2048);
    }
    f32x4 acc[2][4];
#pragma unroll
    for (int si = 0; si < 2; si++)
#pragma unroll
      for (int tj = 0; tj < 4; tj++) acc[si][tj] = (f32x4){0.f, 0.f, 0.f, 0.f};
#pragma unroll
    for (int tj = 0; tj < 4; tj++) {
      bf16x8 b[4];
#pragma unroll
      for (int ks = 0; ks < 4; ks++)
        b[ks] = *(const bf16x8*)&Zsm[(tj * 16 + ln) * 136 + ks * 32 + q * 8];
#pragma unroll
      for (int ks = 0; ks < 4; ks++) {
        acc[0][tj] = __builtin_amdgcn_mfma_f32_16x16x32_bf16(a[0][ks], b[ks], acc[0][tj], 0, 0, 0);
        acc[1][tj] = __builtin_amdgcn_mfma_f32_16x16x32_bf16(a[1][ks], b[ks], acc[1][tj], 0, 0, 0);
      }
    }
#pragma unroll
    for (int si = 0; si < 2; si++)
#pragma unroll
      for (int reg = 0; reg < 4; reg++) {
        float s = 0.f;
#pragma unroll
        for (int tj = 0; tj < 4; tj++) s += __expf(acc[si][tj][reg] * INV_T);
        e[si][reg] += s;
      }
    __syncthreads();
  }
#pragma unroll
  for (int si = 0; si < 2; si++)
#pragma unroll
    for (int reg = 0; reg < 4; reg++) {
#pragma unroll
      for (int off = 8; off > 0; off >>= 1)
        e[si][reg] += __shfl_xor(e[si][reg], off, 16);
    }
  if (ln == 0) {
#pragma unroll
    for (int si = 0; si < 2; si++)
#pragma unroll
      for (int reg = 0; reg < 4; reg++)
        rsP[((size_t)m * 4 + jc) * B_ + i0 + si * 16 + q * 4 + reg] = e[si][reg];
  }
}

// ---------------- per-source loss reduce -> per-block partials ----------------
__global__ __launch_bounds__(256) void lossred_kernel(const float* __restrict__ rsP,
                                                      const float* __restrict__ pos,
                                                      float* __restrict__ lossP) {
  const int s = blockIdx.y;
  const int i = blockIdx.x * 256 + threadIdx.x;
  __shared__ float red[4];
  float denom = -EXP10;
#pragma unroll
  for (int jc = 0; jc < 4; jc++) {
    denom += rsP[(size_t)jc * B_ + i];                      // m = 0 (refl)
    denom += rsP[((size_t)(1 + s) * 4 + jc) * B_ + i];      // m = 1+s
  }
  float val = logf(denom) - pos[s * B_ + i] * INV_T;
  float v = waveReduceSum(val);
  if ((threadIdx.x & 63) == 0) red[threadIdx.x >> 6] = v;
  __syncthreads();
  if (threadIdx.x == 0)
    lossP[s * 16 + blockIdx.x] = red[0] + red[1] + red[2] + red[3];
}

// ---------------- finalize: sum partials + outputs ----------------
__global__ __launch_bounds__(128) void finalize_kernel(const float* __restrict__ cbsumP,
                                                       const float* __restrict__ lossP,
                                                       float* __restrict__ out) {
  const int d = threadIdx.x;
  __shared__ float red[2];
  float acc = 0.0f;
#pragma unroll
  for (int m = 0; m < C_; m++) {
    float v = 0.0f;
#pragma unroll
    for (int blk = 0; blk < 8; blk++) v += cbsumP[(size_t)(m * 8 + blk) * D_ + d];
    acc += v * v;
  }
  float tot = blockReduceSum128(acc, red);
  if (d == 0) out[0] = tot * (1.0f / (3.0f * 512.0f * 512.0f));
  if (d == 1) out[1] = 0.0f;
  if (d >= 2 && d < 5) {
    float l = 0.0f;
#pragma unroll
    for (int x = 0; x < 16; x++) l += lossP[(d - 2) * 16 + x];
    out[d] = l * (1.0f / 4096.0f);
  }
}

extern "C" void kernel_launch(void* const* d_in, const int* in_sizes, int n_in,
                              void* d_out, int out_size, void* d_ws, size_t ws_size,
                              hipStream_t stream) {
  const float* x    = (const float*)d_in[0];
  const float* w1   = (const float*)d_in[1];
  const float* b1   = (const float*)d_in[2];
  const float* w2   = (const float*)d_in[3];
  const float* b2   = (const float*)d_in[4];
  const float* w3   = (const float*)d_in[5];
  const float* b3   = (const float*)d_in[6];
  const float* w4   = (const float*)d_in[7];
  const float* b4   = (const float*)d_in[8];
  const float* qw1  = (const float*)d_in[9];
  const float* qb1  = (const float*)d_in[10];
  const float* qw2  = (const float*)d_in[11];
  const float* cb   = (const float*)d_in[12];
  float* out = (float*)d_out;
  char* base = (char*)d_ws;

  size_t o = 0;
  auto alloc = [&](size_t bytes) { size_t r = o; o += (bytes + 255) & ~(size_t)255; return r; };
  size_t o_xb   = alloc((size_t)S_ * B_ * DIN_ * 2);
  size_t o_wt1  = alloc((size_t)S_ * H1_ * DIN_ * 2);
  size_t o_wt2  = alloc((size_t)S_ * H2_ * H1_ * 2);
  size_t o_wt3  = alloc((size_t)S_ * H3_ * H2_ * 2);
  size_t o_wt4  = alloc((size_t)S_ * D_ * H3_ * 2);
  size_t o_h1b  = alloc((size_t)S_ * B_ * H1_ * 2);
  size_t o_h2b  = alloc((size_t)S_ * B_ * H2_ * 2);
  size_t o_h3b  = alloc((size_t)S_ * B_ * H3_ * 2);
  size_t o_emb  = alloc((size_t)S_ * B_ * D_ * 4);
  size_t o_fus  = alloc((size_t)B_ * D_ * 4);
  size_t o_qs   = alloc((size_t)B_ * D_ * 4);
  size_t o_zb   = alloc((size_t)4 * B_ * D_ * 2);
  size_t o_cbn2 = alloc((size_t)C_ * K_ * 4);
  size_t o_cbb  = alloc((size_t)C_ * K_ * D_ * 2);
  size_t o_rsP  = alloc((size_t)4 * 4 * B_ * 4);
  size_t o_cbsP = alloc((size_t)C_ * 8 * D_ * 4);
  size_t o_lossP= alloc((size_t)S_ * 16 * 4);
  size_t o_pos  = alloc((size_t)S_ * B_ * 4);
  (void)ws_size; (void)in_sizes; (void)n_in; (void)out_size;

  unsigned short* xb  = (unsigned short*)(base + o_xb);
  unsigned short* wt1 = (unsigned short*)(base + o_wt1);
  unsigned short* wt2 = (unsigned short*)(base + o_wt2);
  unsigned short* wt3 = (unsigned short*)(base + o_wt3);
  unsigned short* wt4 = (unsigned short*)(base + o_wt4);
  unsigned short* h1b = (unsigned short*)(base + o_h1b);
  unsigned short* h2b = (unsigned short*)(base + o_h2b);
  unsigned short* h3b = (unsigned short*)(base + o_h3b);
  float* emb   = (float*)(base + o_emb);
  float* fused = (float*)(base + o_fus);
  float* qsum  = (float*)(base + o_qs);
  unsigned short* zb = (unsigned short*)(base + o_zb);
  float* cbn2  = (float*)(base + o_cbn2);
  unsigned short* cbb = (unsigned short*)(base + o_cbb);
  float* rsP   = (float*)(base + o_rsP);
  float* cbsumP= (float*)(base + o_cbsP);
  float* lossP = (float*)(base + o_lossP);
  float* pos   = (float*)(base + o_pos);

  // input conversion + swizzled weights
  cvt_bf16_kernel<<<dim3((S_ * B_ * DIN_) / 1024), 256, 0, stream>>>(x, xb, S_ * B_ * DIN_);
  transpose_w_kernel<<<dim3(DIN_ / 32, H1_ / 32, S_), dim3(32, 8), 0, stream>>>(w1, wt1, DIN_, H1_);
  transpose_w_kernel<<<dim3(H1_ / 32, H2_ / 32, S_), dim3(32, 8), 0, stream>>>(w2, wt2, H1_, H2_);
  transpose_w_kernel<<<dim3(H2_ / 32, H3_ / 32, S_), dim3(32, 8), 0, stream>>>(w3, wt3, H2_, H3_);
  transpose_w_kernel<<<dim3(H3_ / 32, D_ / 32, S_), dim3(32, 8), 0, stream>>>(w4, wt4, H3_, D_);

  // codebook norms + bf16 codebook + cbsum partials
  cbns_kernel<<<dim3(C_ * 8), 512, 0, stream>>>(cb, cbn2, cbsumP, cbb);

  // encoder MLP via LDS-staged MFMA (BK=64, swizzled weights)
  const int Mtot = S_ * B_;
  gemm_lds_kernel<<<dim3(H1_ / 128, Mtot / 64), 256, 0, stream>>>(xb, wt1, b1, h1b, DIN_, H1_, 1, 0);
  gemm_lds_kernel<<<dim3(H2_ / 128, Mtot / 64), 256, 0, stream>>>(h1b, wt2, b2, h2b, H1_, H2_, 1, 0);
  gemm_lds_kernel<<<dim3(H3_ / 128, Mtot / 64), 256, 0, stream>>>(h2b, wt3, b3, h3b, H2_, H3_, 1, 0);
  gemm_lds_kernel<<<dim3(D_ / 128, Mtot / 64), 256, 0, stream>>>(h3b, wt4, b4, emb, H3_, D_, 0, 1);

  // fused attention score + softmax + fuse
  score_fuse_kernel<<<dim3(B_ / 4), 256, 0, stream>>>(emb, qw1, qb1, qw2, fused);

  // residual VQ (MFMA distance GEMM)
  vq_mfma_kernel<<<dim3(B_ / 16), 512, 0, stream>>>(fused, cb, cbb, cbn2, qsum);

  // fused normalize + pos
  normpos_kernel<<<dim3(B_), 256, 0, stream>>>(qsum, emb, zb, pos);

  // contrastive rowsum partials
  contrast_mfma_kernel<<<dim3(4, 32, 4), 256, 0, stream>>>(zb, rsP);

  // per-source contrastive partials
  lossred_kernel<<<dim3(B_ / 256, S_), 256, 0, stream>>>(rsP, pos, lossP);

  finalize_kernel<<<dim3(1), 128, 0, stream>>>(cbsumP, lossP, out);
}

// Round 13
// 248.967 us; speedup vs baseline: 1.2671x; 1.0148x over previous
//
#include <hip/hip_runtime.h>
#include <hip/hip_bf16.h>

// Problem constants
#define S_   3
#define B_   4096
#define DIN_ 1024
#define H1_  512
#define H2_  384
#define H3_  256
#define D_   128
#define K_   512
#define C_   3
#define INV_T 10.0f          // 1/TEMP
#define EPS_  1e-12f
#define EXP10 22026.465794806718f   // exp(1/T), diag(refl) analytically

typedef float f32x4 __attribute__((ext_vector_type(4)));
typedef short bf16x8 __attribute__((ext_vector_type(8)));

__device__ __forceinline__ unsigned short f2bf(float f) {
  unsigned int u = __float_as_uint(f);
  u = (u + 0x7FFF + ((u >> 16) & 1)) >> 16;   // round-to-nearest-even
  return (unsigned short)u;
}

// ---------------- reduction helpers ----------------
__device__ __forceinline__ float waveReduceSum(float v) {
#pragma unroll
  for (int off = 32; off > 0; off >>= 1) v += __shfl_down(v, off, 64);
  return v;
}

__device__ __forceinline__ float waveXorSum(float v) {
#pragma unroll
  for (int off = 32; off > 0; off >>= 1) v += __shfl_xor(v, off, 64);
  return v;
}

// ---------------- fused prep: x fp32->bf16 + all 4 weight transposes ----------------
// grid = 12288 (cvt) + 1536 (w1) + 576 (w2) + 288 (w3) + 96 (w4) = 14784 blocks.
// Wsw layout per (s, n-block of 128, k-tile of 64): 8192 shorts;
// offset = tile*8192 + ksl*4096 + (n&127)*32 + (k&31), ksl = (k>>5)&1.
__global__ __launch_bounds__(256) void prep_kernel(
    const float* __restrict__ x, unsigned short* __restrict__ xb,
    const float* __restrict__ w1, unsigned short* __restrict__ wt1,
    const float* __restrict__ w2, unsigned short* __restrict__ wt2,
    const float* __restrict__ w3, unsigned short* __restrict__ wt3,
    const float* __restrict__ w4, unsigned short* __restrict__ wt4) {
  __shared__ float tt[32][33];
  const int t = threadIdx.x;
  int blk = blockIdx.x;
  const int NCVT = (S_ * B_ * DIN_) / 1024;   // 12288
  if (blk < NCVT) {
    int i = (blk * 256 + t) * 4;
    float4 v = *(const float4*)(x + i);
    xb[i + 0] = f2bf(v.x); xb[i + 1] = f2bf(v.y);
    xb[i + 2] = f2bf(v.z); xb[i + 3] = f2bf(v.w);
    return;
  }
  blk -= NCVT;
  const float* W; unsigned short* Wt; int K, N;
  if (blk < 1536) { W = w1; Wt = wt1; K = DIN_; N = H1_; }
  else {
    blk -= 1536;
    if (blk < 576) { W = w2; Wt = wt2; K = H1_; N = H2_; }
    else {
      blk -= 576;
      if (blk < 288) { W = w3; Wt = wt3; K = H2_; N = H3_; }
      else { blk -= 288; W = w4; Wt = wt4; K = H3_; N = D_; }
    }
  }
  const int kx_n = K / 32, ny_n = N / 32;
  const int kx = blk % kx_n;
  const int ny = (blk / kx_n) % ny_n;
  const int s  = blk / (kx_n * ny_n);
  const int k0 = kx * 32, n0 = ny * 32;
  const int tx = t & 31, ty = t >> 5;        // 32 x 8
  const float* Ws = W + (size_t)s * K * N;
  const int nb = N >> 7, kb = K >> 6;
#pragma unroll
  for (int i = 0; i < 4; i++)
    tt[ty + 8 * i][tx] = Ws[(size_t)(k0 + ty + 8 * i) * N + n0 + tx];
  __syncthreads();
  const int k = k0 + tx;
  const int kt = k >> 6, ksl = (k >> 5) & 1;
#pragma unroll
  for (int i = 0; i < 4; i++) {
    int n = n0 + ty + 8 * i;
    size_t dst = ((size_t)(s * nb + (n >> 7)) * kb + kt) * 8192 +
                 (size_t)ksl * 4096 + (size_t)(n & 127) * 32 + (k & 31);
    Wt[dst] = f2bf(tt[tx][ty + 8 * i]);
  }
}

// ---------------- LDS-staged MFMA GEMM, BK=64, swizzled weights ----------------
__global__ __launch_bounds__(256) void gemm_lds_kernel(
    const unsigned short* __restrict__ A, const unsigned short* __restrict__ Wsw,
    const float* __restrict__ bias, void* __restrict__ Y,
    int K, int N, int relu, int out_f32) {
  const int t = threadIdx.x;
  const int lane = t & 63;
  const int w = t >> 6;
  const int ln = lane & 15, q = lane >> 4;
  const int wm = w >> 1, wn = w & 1;
  const int n0 = blockIdx.x * 128;
  const int mblk = blockIdx.y;
  const int s = mblk >> 6;                  // 4096/64 = 64 m-blocks per source
  const int m0 = mblk * 64;
  const int nb = N >> 7, kb = K >> 6;

  const unsigned short* Ag = A + (size_t)m0 * K;
  const unsigned short* Bt = Wsw + ((size_t)(s * nb + blockIdx.x) * kb) * 8192;
  const float* bs = bias + (size_t)s * N;

  __shared__ unsigned short Asm[2 * 64 * 32];
  __shared__ unsigned short Bsm[2 * 128 * 32];

  const int arow0 = t >> 3, ak8 = t & 7;
  const int aL0 = (ak8 >> 2) * 2048 + arow0 * 32 + (ak8 & 3) * 8;
  const size_t gA0 = (size_t)arow0 * K + ak8 * 8;

  bf16x8 ra0 = *(const bf16x8*)(Ag + gA0);
  bf16x8 ra1 = *(const bf16x8*)(Ag + gA0 + (size_t)32 * K);
  bf16x8 rb[4];
#pragma unroll
  for (int p = 0; p < 4; p++)
    rb[p] = *(const bf16x8*)(Bt + (size_t)(p * 256 + t) * 8);

  f32x4 acc[2][4];
#pragma unroll
  for (int i = 0; i < 2; i++)
#pragma unroll
    for (int j = 0; j < 4; j++) acc[i][j] = (f32x4){0.f, 0.f, 0.f, 0.f};

  for (int kt = 0; kt < kb; kt++) {
    *(bf16x8*)&Asm[aL0] = ra0;
    *(bf16x8*)&Asm[aL0 + 1024] = ra1;
#pragma unroll
    for (int p = 0; p < 4; p++)
      *(bf16x8*)&Bsm[(size_t)(p * 256 + t) * 8] = rb[p];
    __syncthreads();
    if (kt + 1 < kb) {
      const size_t g = gA0 + (size_t)(kt + 1) * 64;
      ra0 = *(const bf16x8*)(Ag + g);
      ra1 = *(const bf16x8*)(Ag + g + (size_t)32 * K);
      const unsigned short* Bn = Bt + (size_t)(kt + 1) * 8192;
#pragma unroll
      for (int p = 0; p < 4; p++)
        rb[p] = *(const bf16x8*)(Bn + (size_t)(p * 256 + t) * 8);
    }
    bf16x8 af[2][2], bf[4][2];
#pragma unroll
    for (int ti = 0; ti < 2; ti++)
#pragma unroll
      for (int ksl = 0; ksl < 2; ksl++)
        af[ti][ksl] = *(const bf16x8*)&Asm[ksl * 2048 + (wm * 32 + ti * 16 + ln) * 32 + q * 8];
#pragma unroll
    for (int tj = 0; tj < 4; tj++)
#pragma unroll
      for (int ksl = 0; ksl < 2; ksl++)
        bf[tj][ksl] = *(const bf16x8*)&Bsm[ksl * 4096 + (wn * 64 + tj * 16 + ln) * 32 + q * 8];
#pragma unroll
    for (int ksl = 0; ksl < 2; ksl++)
#pragma unroll
      for (int ti = 0; ti < 2; ti++)
#pragma unroll
        for (int tj = 0; tj < 4; tj++)
          acc[ti][tj] = __builtin_amdgcn_mfma_f32_16x16x32_bf16(af[ti][ksl], bf[tj][ksl], acc[ti][tj], 0, 0, 0);
    __syncthreads();
  }

#pragma unroll
  for (int ti = 0; ti < 2; ti++)
#pragma unroll
    for (int tj = 0; tj < 4; tj++) {
      const int cc = n0 + wn * 64 + tj * 16 + ln;
      const float bv = bs[cc];
#pragma unroll
      for (int reg = 0; reg < 4; reg++) {
        const int r = m0 + wm * 32 + ti * 16 + q * 4 + reg;
        float v = acc[ti][tj][reg] + bv;
        if (relu) v = fmaxf(v, 0.0f);
        if (out_f32) ((float*)Y)[(size_t)r * N + cc] = v;
        else ((unsigned short*)Y)[(size_t)r * N + cc] = f2bf(v);
      }
    }
}

// ---------------- fused attention score + softmax + fuse (4 b per block) --------
__global__ __launch_bounds__(256) void score_fuse_kernel(
    const float* __restrict__ emb, const float* __restrict__ qw1,
    const float* __restrict__ qb1, const float* __restrict__ qw2,
    float* __restrict__ fused) {
  const int b0 = blockIdx.x * 4;
  const int t = threadIdx.x;
  const int g = t >> 7, d = t & 127;
  __shared__ float e[12][D_];
  __shared__ float red[4][6];
  __shared__ float sc[12];
#pragma unroll
  for (int i = 0; i < 3; i++) {
    int idx = i * 512 + t * 2;
    int r = idx >> 7, dd = idx & 127;
    int s = r >> 2, bi = r & 3;
    *(float2*)&e[r][dd] = *(const float2*)(emb + ((size_t)(s * B_ + b0 + bi)) * D_ + dd);
  }
  __syncthreads();
  float acc[6] = {0.f, 0.f, 0.f, 0.f, 0.f, 0.f};
  for (int i = 0; i < D_; i++) {
    float w = qw1[i * D_ + d];
#pragma unroll
    for (int j = 0; j < 6; j++) acc[j] = fmaf(e[g * 6 + j][i], w, acc[j]);
  }
  const float qb = qb1[d], q2 = qw2[d];
  float val[6];
#pragma unroll
  for (int j = 0; j < 6; j++) val[j] = tanhf(acc[j] + qb) * q2;
  const int wave = t >> 6;
#pragma unroll
  for (int j = 0; j < 6; j++) {
    float v = waveReduceSum(val[j]);
    if ((t & 63) == 0) red[wave][j] = v;
  }
  __syncthreads();
  if (t < 12) {
    int gg = t / 6, j = t % 6;
    sc[gg * 6 + j] = red[2 * gg][j] + red[2 * gg + 1][j];
  }
  __syncthreads();
#pragma unroll
  for (int p = 0; p < 2; p++) {
    int idx = p * 256 + t;
    int bi = idx >> 7, dd = idx & 127;
    float s0 = sc[bi], s1 = sc[4 + bi], s2 = sc[8 + bi];
    float mx = fmaxf(s0, fmaxf(s1, s2));
    float e0 = __expf(s0 - mx), e1 = __expf(s1 - mx), e2 = __expf(s2 - mx);
    float inv = 1.0f / (e0 + e1 + e2);
    fused[(size_t)(b0 + bi) * D_ + dd] =
        (e0 * e[bi][dd] + e1 * e[4 + bi][dd] + e2 * e[8 + bi][dd]) * inv;
  }
}

// ---------------- fused codebook norms + bf16 convert + column-sum partials -----
__global__ __launch_bounds__(512) void cbns_kernel(const float* __restrict__ cb,
                                                   float* __restrict__ cbn2,
                                                   float* __restrict__ cbsumP,
                                                   unsigned short* __restrict__ cbb) {
  const int m = blockIdx.x >> 3;
  const int k0 = (blockIdx.x & 7) * 64;
  const int t = threadIdx.x, w = t >> 6, lane = t & 63;
  __shared__ float invn[64];
#pragma unroll
  for (int r = w * 8; r < w * 8 + 8; r++) {
    int k = k0 + r;
    float2 v = *(const float2*)(cb + ((size_t)m * K_ + k) * D_ + lane * 2);
    unsigned short* crow = cbb + ((size_t)m * K_ + k) * D_;
    crow[lane * 2 + 0] = f2bf(v.x);
    crow[lane * 2 + 1] = f2bf(v.y);
    float n2 = waveXorSum(v.x * v.x + v.y * v.y);
    if (lane == 0) {
      cbn2[m * K_ + k] = n2;
      invn[r] = 1.0f / fmaxf(sqrtf(n2), EPS_);
    }
  }
  __syncthreads();
  if (t < D_) {
    float acc = 0.0f;
    for (int r = 0; r < 64; r++)
      acc += cb[((size_t)m * K_ + k0 + r) * D_ + t] * invn[r];
    cbsumP[(size_t)blockIdx.x * D_ + t] = acc;
  }
}

// ---------------- residual VQ: MFMA distance GEMM ----------------
__global__ __launch_bounds__(512) void vq_mfma_kernel(
    const float* __restrict__ fused, const float* __restrict__ cb,
    const unsigned short* __restrict__ cbb, const float* __restrict__ cbn2,
    float* __restrict__ qsum) {
  const int r0 = blockIdx.x * 16;
  const int t = threadIdx.x;
  const int w = t >> 6, lane = t & 63;
  const int ln = lane & 15, q = lane >> 4;
  __shared__ float resv[16][D_];
  __shared__ unsigned short resb[16][D_];
  __shared__ float candd[8][16];
  __shared__ int candk[8][16];
  __shared__ int bestk[16];

  {
    int idx = t * 4;
    int r = idx >> 7, dd = idx & 127;
    float4 v = *(const float4*)(fused + (size_t)(r0 + r) * D_ + dd);
    *(float4*)&resv[r][dd] = v;
    resb[r][dd + 0] = f2bf(v.x); resb[r][dd + 1] = f2bf(v.y);
    resb[r][dd + 2] = f2bf(v.z); resb[r][dd + 3] = f2bf(v.w);
  }
  __syncthreads();

  for (int c = 0; c < C_; c++) {
    bf16x8 a[4];
#pragma unroll
    for (int ks = 0; ks < 4; ks++)
      a[ks] = *(const bf16x8*)&resb[ln][ks * 32 + q * 8];
    f32x4 acc[4];
#pragma unroll
    for (int tt = 0; tt < 4; tt++) acc[tt] = (f32x4){0.f, 0.f, 0.f, 0.f};
#pragma unroll
    for (int tt = 0; tt < 4; tt++) {
      const int n = w * 64 + tt * 16 + ln;
      const unsigned short* bp = cbb + ((size_t)c * K_ + n) * D_;
#pragma unroll
      for (int ks = 0; ks < 4; ks++) {
        bf16x8 b = *(const bf16x8*)(bp + ks * 32 + q * 8);
        acc[tt] = __builtin_amdgcn_mfma_f32_16x16x32_bf16(a[ks], b, acc[tt], 0, 0, 0);
      }
    }
    float bd[4]; int bk[4];
#pragma unroll
    for (int reg = 0; reg < 4; reg++) { bd[reg] = 3.4e38f; bk[reg] = 0x7fffffff; }
#pragma unroll
    for (int tt = 0; tt < 4; tt++) {
      const int col = w * 64 + tt * 16 + ln;
      const float n2 = cbn2[c * K_ + col];
#pragma unroll
      for (int reg = 0; reg < 4; reg++) {
        float dist = n2 - 2.0f * acc[tt][reg];
        if (dist < bd[reg] || (dist == bd[reg] && col < bk[reg])) { bd[reg] = dist; bk[reg] = col; }
      }
    }
#pragma unroll
    for (int reg = 0; reg < 4; reg++) {
#pragma unroll
      for (int off = 8; off > 0; off >>= 1) {
        float d1 = __shfl_down(bd[reg], off, 16);
        int k1 = __shfl_down(bk[reg], off, 16);
        if (d1 < bd[reg] || (d1 == bd[reg] && k1 < bk[reg])) { bd[reg] = d1; bk[reg] = k1; }
      }
      if (ln == 0) { candd[w][q * 4 + reg] = bd[reg]; candk[w][q * 4 + reg] = bk[reg]; }
    }
    __syncthreads();
    if (w == 0) {
      int row = lane >> 2, g = lane & 3;
      float d0 = candd[2 * g][row]; int k0 = candk[2 * g][row];
      float d1 = candd[2 * g + 1][row]; int k1 = candk[2 * g + 1][row];
      if (d1 < d0 || (d1 == d0 && k1 < k0)) { d0 = d1; k0 = k1; }
#pragma unroll
      for (int off = 2; off > 0; off >>= 1) {
        float dn = __shfl_down(d0, off, 4);
        int kn = __shfl_down(k0, off, 4);
        if (dn < d0 || (dn == d0 && kn < k0)) { d0 = dn; k0 = kn; }
      }
      if (g == 0) bestk[row] = k0;
    }
    __syncthreads();
    {
      int idx = t * 4;
      int r = idx >> 7, dd = idx & 127;
      const float4 qv = *(const float4*)(cb + ((size_t)c * K_ + bestk[r]) * D_ + dd);
      float4 rv = *(float4*)&resv[r][dd];
      rv.x -= qv.x; rv.y -= qv.y; rv.z -= qv.z; rv.w -= qv.w;
      *(float4*)&resv[r][dd] = rv;
      resb[r][dd + 0] = f2bf(rv.x); resb[r][dd + 1] = f2bf(rv.y);
      resb[r][dd + 2] = f2bf(rv.z); resb[r][dd + 3] = f2bf(rv.w);
    }
    __syncthreads();
  }

  {
    int idx = t * 4;
    int r = idx >> 7, dd = idx & 127;
    float4 f = *(const float4*)(fused + (size_t)(r0 + r) * D_ + dd);
    float4 rv = *(float4*)&resv[r][dd];
    f.x -= rv.x; f.y -= rv.y; f.z -= rv.z; f.w -= rv.w;
    *(float4*)(qsum + (size_t)(r0 + r) * D_ + dd) = f;
  }
}

// ---------------- fused normalize + pos: block per b, wave per row ----------------
__global__ __launch_bounds__(256) void normpos_kernel(
    const float* __restrict__ qsum, const float* __restrict__ emb,
    unsigned short* __restrict__ zb, float* __restrict__ pos) {
  const int b = blockIdx.x;
  const int w = threadIdx.x >> 6, lane = threadIdx.x & 63;
  __shared__ float zl[4][D_];
  const float* src = (w == 0) ? (qsum + (size_t)b * D_)
                              : (emb + (size_t)((w - 1) * B_ + b) * D_);
  float2 v = *(const float2*)(src + lane * 2);
  float n2 = waveXorSum(v.x * v.x + v.y * v.y);
  float inv = 1.0f / fmaxf(sqrtf(n2), EPS_);
  float zx = v.x * inv, zy = v.y * inv;
  const size_t g = (size_t)w * B_ + b;
  zb[g * D_ + lane * 2 + 0] = f2bf(zx);
  zb[g * D_ + lane * 2 + 1] = f2bf(zy);
  zl[w][lane * 2] = zx; zl[w][lane * 2 + 1] = zy;
  __syncthreads();
  if (w >= 1) {
    float2 a = *(const float2*)&zl[0][lane * 2];
    float dsum = waveXorSum(a.x * zx + a.y * zy);
    if (lane == 0) pos[(w - 1) * B_ + b] = dsum;
  }
}

// ---------------- contrastive exp-rowsums: LDS-staged B tiles ----------------
__global__ __launch_bounds__(256) void contrast_mfma_kernel(
    const unsigned short* __restrict__ zb, float* __restrict__ rsP) {
  const int jc = blockIdx.x, ib = blockIdx.y, m = blockIdx.z;
  const int t = threadIdx.x;
  const int w = t >> 6, lane = t & 63;
  const int ln = lane & 15, q = lane >> 4;
  const int i0 = ib * 128 + w * 32;
  const unsigned short* Za = zb;
  const unsigned short* Zm = zb + (size_t)m * B_ * D_;

  __shared__ unsigned short Zsm[64 * 136];

  bf16x8 a[2][4];
#pragma unroll
  for (int si = 0; si < 2; si++)
#pragma unroll
    for (int ks = 0; ks < 4; ks++)
      a[si][ks] = *(const bf16x8*)(Za + (size_t)(i0 + si * 16 + ln) * D_ + ks * 32 + q * 8);

  const unsigned short* tb = Zm + (size_t)(jc * 1024) * D_;
  bf16x8 rz[4];
#pragma unroll
  for (int p = 0; p < 4; p++)
    rz[p] = *(const bf16x8*)(tb + t * 8 + p * 2048);

  float e[2][4] = {};
  for (int jt = 0; jt < 16; jt++) {
#pragma unroll
    for (int p = 0; p < 4; p++) {
      int c = t + p * 256;
      *(bf16x8*)&Zsm[(c >> 4) * 136 + (c & 15) * 8] = rz[p];
    }
    __syncthreads();
    if (jt + 1 < 16) {
      const unsigned short* tn = Zm + (size_t)(jc * 1024 + (jt + 1) * 64) * D_;
#pragma unroll
      for (int p = 0; p < 4; p++)
        rz[p] = *(const bf16x8*)(tn + t * 8 + p * 2048);
    }
    f32x4 acc[2][4];
#pragma unroll
    for (int si = 0; si < 2; si++)
#pragma unroll
      for (int tj = 0; tj < 4; tj++) acc[si][tj] = (f32x4){0.f, 0.f, 0.f, 0.f};
#pragma unroll
    for (int tj = 0; tj < 4; tj++) {
      bf16x8 b[4];
#pragma unroll
      for (int ks = 0; ks < 4; ks++)
        b[ks] = *(const bf16x8*)&Zsm[(tj * 16 + ln) * 136 + ks * 32 + q * 8];
#pragma unroll
      for (int ks = 0; ks < 4; ks++) {
        acc[0][tj] = __builtin_amdgcn_mfma_f32_16x16x32_bf16(a[0][ks], b[ks], acc[0][tj], 0, 0, 0);
        acc[1][tj] = __builtin_amdgcn_mfma_f32_16x16x32_bf16(a[1][ks], b[ks], acc[1][tj], 0, 0, 0);
      }
    }
#pragma unroll
    for (int si = 0; si < 2; si++)
#pragma unroll
      for (int reg = 0; reg < 4; reg++) {
        float s = 0.f;
#pragma unroll
        for (int tj = 0; tj < 4; tj++) s += __expf(acc[si][tj][reg] * INV_T);
        e[si][reg] += s;
      }
    __syncthreads();
  }
#pragma unroll
  for (int si = 0; si < 2; si++)
#pragma unroll
    for (int reg = 0; reg < 4; reg++) {
#pragma unroll
      for (int off = 8; off > 0; off >>= 1)
        e[si][reg] += __shfl_xor(e[si][reg], off, 16);
    }
  if (ln == 0) {
#pragma unroll
    for (int si = 0; si < 2; si++)
#pragma unroll
      for (int reg = 0; reg < 4; reg++)
        rsP[((size_t)m * 4 + jc) * B_ + i0 + si * 16 + q * 4 + reg] = e[si][reg];
  }
}

// ---------------- fused loss reduce + finalize (4 blocks) ----------------
// block 0: codebook loss -> out[0], out[1]; block 1+s: contrastive source s -> out[2+s].
__global__ __launch_bounds__(256) void final2_kernel(const float* __restrict__ rsP,
                                                     const float* __restrict__ pos,
                                                     const float* __restrict__ cbsumP,
                                                     float* __restrict__ out) {
  const int blk = blockIdx.x;
  const int t = threadIdx.x;
  __shared__ float red[4];
  if (blk == 0) {
    float acc = 0.0f;
    if (t < D_) {
#pragma unroll
      for (int m = 0; m < C_; m++) {
        float v = 0.0f;
#pragma unroll
        for (int b8 = 0; b8 < 8; b8++) v += cbsumP[(size_t)(m * 8 + b8) * D_ + t];
        acc += v * v;
      }
    }
    float v = waveReduceSum(acc);
    if ((t & 63) == 0) red[t >> 6] = v;
    __syncthreads();
    if (t == 0) {
      out[0] = (red[0] + red[1] + red[2] + red[3]) * (1.0f / (3.0f * 512.0f * 512.0f));
      out[1] = 0.0f;
    }
  } else {
    const int s = blk - 1;
    float acc = 0.0f;
    for (int it = 0; it < 16; it++) {
      const int i = it * 256 + t;
      float denom = -EXP10;
#pragma unroll
      for (int jc = 0; jc < 4; jc++) {
        denom += rsP[(size_t)jc * B_ + i];                      // m = 0 (refl)
        denom += rsP[((size_t)(1 + s) * 4 + jc) * B_ + i];      // m = 1+s
      }
      acc += logf(denom) - pos[s * B_ + i] * INV_T;
    }
    float v = waveReduceSum(acc);
    if ((t & 63) == 0) red[t >> 6] = v;
    __syncthreads();
    if (t == 0)
      out[2 + s] = (red[0] + red[1] + red[2] + red[3]) * (1.0f / 4096.0f);
  }
}

extern "C" void kernel_launch(void* const* d_in, const int* in_sizes, int n_in,
                              void* d_out, int out_size, void* d_ws, size_t ws_size,
                              hipStream_t stream) {
  const float* x    = (const float*)d_in[0];
  const float* w1   = (const float*)d_in[1];
  const float* b1   = (const float*)d_in[2];
  const float* w2   = (const float*)d_in[3];
  const float* b2   = (const float*)d_in[4];
  const float* w3   = (const float*)d_in[5];
  const float* b3   = (const float*)d_in[6];
  const float* w4   = (const float*)d_in[7];
  const float* b4   = (const float*)d_in[8];
  const float* qw1  = (const float*)d_in[9];
  const float* qb1  = (const float*)d_in[10];
  const float* qw2  = (const float*)d_in[11];
  const float* cb   = (const float*)d_in[12];
  float* out = (float*)d_out;
  char* base = (char*)d_ws;

  size_t o = 0;
  auto alloc = [&](size_t bytes) { size_t r = o; o += (bytes + 255) & ~(size_t)255; return r; };
  size_t o_xb   = alloc((size_t)S_ * B_ * DIN_ * 2);
  size_t o_wt1  = alloc((size_t)S_ * H1_ * DIN_ * 2);
  size_t o_wt2  = alloc((size_t)S_ * H2_ * H1_ * 2);
  size_t o_wt3  = alloc((size_t)S_ * H3_ * H2_ * 2);
  size_t o_wt4  = alloc((size_t)S_ * D_ * H3_ * 2);
  size_t o_h1b  = alloc((size_t)S_ * B_ * H1_ * 2);
  size_t o_h2b  = alloc((size_t)S_ * B_ * H2_ * 2);
  size_t o_h3b  = alloc((size_t)S_ * B_ * H3_ * 2);
  size_t o_emb  = alloc((size_t)S_ * B_ * D_ * 4);
  size_t o_fus  = alloc((size_t)B_ * D_ * 4);
  size_t o_qs   = alloc((size_t)B_ * D_ * 4);
  size_t o_zb   = alloc((size_t)4 * B_ * D_ * 2);
  size_t o_cbn2 = alloc((size_t)C_ * K_ * 4);
  size_t o_cbb  = alloc((size_t)C_ * K_ * D_ * 2);
  size_t o_rsP  = alloc((size_t)4 * 4 * B_ * 4);
  size_t o_cbsP = alloc((size_t)C_ * 8 * D_ * 4);
  size_t o_pos  = alloc((size_t)S_ * B_ * 4);
  (void)ws_size; (void)in_sizes; (void)n_in; (void)out_size;

  unsigned short* xb  = (unsigned short*)(base + o_xb);
  unsigned short* wt1 = (unsigned short*)(base + o_wt1);
  unsigned short* wt2 = (unsigned short*)(base + o_wt2);
  unsigned short* wt3 = (unsigned short*)(base + o_wt3);
  unsigned short* wt4 = (unsigned short*)(base + o_wt4);
  unsigned short* h1b = (unsigned short*)(base + o_h1b);
  unsigned short* h2b = (unsigned short*)(base + o_h2b);
  unsigned short* h3b = (unsigned short*)(base + o_h3b);
  float* emb   = (float*)(base + o_emb);
  float* fused = (float*)(base + o_fus);
  float* qsum  = (float*)(base + o_qs);
  unsigned short* zb = (unsigned short*)(base + o_zb);
  float* cbn2  = (float*)(base + o_cbn2);
  unsigned short* cbb = (unsigned short*)(base + o_cbb);
  float* rsP   = (float*)(base + o_rsP);
  float* cbsumP= (float*)(base + o_cbsP);
  float* pos   = (float*)(base + o_pos);

  // fused prep: x->bf16 + all weight transposes (one launch)
  const int prep_blocks = (S_ * B_ * DIN_) / 1024 + 1536 + 576 + 288 + 96;
  prep_kernel<<<dim3(prep_blocks), 256, 0, stream>>>(x, xb, w1, wt1, w2, wt2, w3, wt3, w4, wt4);

  // codebook norms + bf16 codebook + cbsum partials
  cbns_kernel<<<dim3(C_ * 8), 512, 0, stream>>>(cb, cbn2, cbsumP, cbb);

  // encoder MLP via LDS-staged MFMA (BK=64, swizzled weights)
  const int Mtot = S_ * B_;
  gemm_lds_kernel<<<dim3(H1_ / 128, Mtot / 64), 256, 0, stream>>>(xb, wt1, b1, h1b, DIN_, H1_, 1, 0);
  gemm_lds_kernel<<<dim3(H2_ / 128, Mtot / 64), 256, 0, stream>>>(h1b, wt2, b2, h2b, H1_, H2_, 1, 0);
  gemm_lds_kernel<<<dim3(H3_ / 128, Mtot / 64), 256, 0, stream>>>(h2b, wt3, b3, h3b, H2_, H3_, 1, 0);
  gemm_lds_kernel<<<dim3(D_ / 128, Mtot / 64), 256, 0, stream>>>(h3b, wt4, b4, emb, H3_, D_, 0, 1);

  // fused attention score + softmax + fuse
  score_fuse_kernel<<<dim3(B_ / 4), 256, 0, stream>>>(emb, qw1, qb1, qw2, fused);

  // residual VQ (MFMA distance GEMM)
  vq_mfma_kernel<<<dim3(B_ / 16), 512, 0, stream>>>(fused, cb, cbb, cbn2, qsum);

  // fused normalize + pos
  normpos_kernel<<<dim3(B_), 256, 0, stream>>>(qsum, emb, zb, pos);

  // contrastive rowsum partials
  contrast_mfma_kernel<<<dim3(4, 32, 4), 256, 0, stream>>>(zb, rsP);

  // fused loss reduce + finalize
  final2_kernel<<<dim3(4), 256, 0, stream>>>(rsP, pos, cbsumP, out);
}

// Round 14
// 247.201 us; speedup vs baseline: 1.2762x; 1.0071x over previous
//
#include <hip/hip_runtime.h>
#include <hip/hip_bf16.h>

// Problem constants
#define S_   3
#define B_   4096
#define DIN_ 1024
#define H1_  512
#define H2_  384
#define H3_  256
#define D_   128
#define K_   512
#define C_   3
#define INV_T 10.0f          // 1/TEMP
#define EPS_  1e-12f
#define EXP10 22026.465794806718f   // exp(1/T), diag(refl) analytically

typedef float f32x4 __attribute__((ext_vector_type(4)));
typedef short bf16x8 __attribute__((ext_vector_type(8)));

__device__ __forceinline__ unsigned short f2bf(float f) {
  unsigned int u = __float_as_uint(f);
  u = (u + 0x7FFF + ((u >> 16) & 1)) >> 16;   // round-to-nearest-even
  return (unsigned short)u;
}

// async 16B-per-lane global -> LDS (wave-uniform base + lane*16 on both sides)
__device__ __forceinline__ void gl2lds16(const unsigned short* g, unsigned short* l) {
  __builtin_amdgcn_global_load_lds(
      (const __attribute__((address_space(1))) void*)g,
      (__attribute__((address_space(3))) void*)l, 16, 0, 0);
}

// ---------------- reduction helpers ----------------
__device__ __forceinline__ float waveReduceSum(float v) {
#pragma unroll
  for (int off = 32; off > 0; off >>= 1) v += __shfl_down(v, off, 64);
  return v;
}

__device__ __forceinline__ float waveXorSum(float v) {
#pragma unroll
  for (int off = 32; off > 0; off >>= 1) v += __shfl_xor(v, off, 64);
  return v;
}

// ---------------- fused prep: x fp32->bf16 + all 4 weight transposes ----------------
__global__ __launch_bounds__(256) void prep_kernel(
    const float* __restrict__ x, unsigned short* __restrict__ xb,
    const float* __restrict__ w1, unsigned short* __restrict__ wt1,
    const float* __restrict__ w2, unsigned short* __restrict__ wt2,
    const float* __restrict__ w3, unsigned short* __restrict__ wt3,
    const float* __restrict__ w4, unsigned short* __restrict__ wt4) {
  __shared__ float tt[32][33];
  const int t = threadIdx.x;
  int blk = blockIdx.x;
  const int NCVT = (S_ * B_ * DIN_) / 1024;   // 12288
  if (blk < NCVT) {
    int i = (blk * 256 + t) * 4;
    float4 v = *(const float4*)(x + i);
    xb[i + 0] = f2bf(v.x); xb[i + 1] = f2bf(v.y);
    xb[i + 2] = f2bf(v.z); xb[i + 3] = f2bf(v.w);
    return;
  }
  blk -= NCVT;
  const float* W; unsigned short* Wt; int K, N;
  if (blk < 1536) { W = w1; Wt = wt1; K = DIN_; N = H1_; }
  else {
    blk -= 1536;
    if (blk < 576) { W = w2; Wt = wt2; K = H1_; N = H2_; }
    else {
      blk -= 576;
      if (blk < 288) { W = w3; Wt = wt3; K = H2_; N = H3_; }
      else { blk -= 288; W = w4; Wt = wt4; K = H3_; N = D_; }
    }
  }
  const int kx_n = K / 32, ny_n = N / 32;
  const int kx = blk % kx_n;
  const int ny = (blk / kx_n) % ny_n;
  const int s  = blk / (kx_n * ny_n);
  const int k0 = kx * 32, n0 = ny * 32;
  const int tx = t & 31, ty = t >> 5;        // 32 x 8
  const float* Ws = W + (size_t)s * K * N;
  const int nb = N >> 7, kb = K >> 6;
#pragma unroll
  for (int i = 0; i < 4; i++)
    tt[ty + 8 * i][tx] = Ws[(size_t)(k0 + ty + 8 * i) * N + n0 + tx];
  __syncthreads();
  const int k = k0 + tx;
  const int kt = k >> 6, ksl = (k >> 5) & 1;
#pragma unroll
  for (int i = 0; i < 4; i++) {
    int n = n0 + ty + 8 * i;
    size_t dst = ((size_t)(s * nb + (n >> 7)) * kb + kt) * 8192 +
                 (size_t)ksl * 4096 + (size_t)(n & 127) * 32 + (k & 31);
    Wt[dst] = f2bf(tt[tx][ty + 8 * i]);
  }
}

// ---------------- LDS-staged MFMA GEMM, BK=64, async B via global_load_lds -------
// B tiles are chunk-linear in both global (swizzled Wsw) and LDS -> satisfies the
// wave-uniform-base + lane*16 contract. Double-buffered Bsm: tile kt+1 issued
// right after the first barrier so the async copy overlaps this tile's MFMAs.
// A staging keeps the register-prefetch path (not lane-linear).
__global__ __launch_bounds__(256) void gemm_lds_kernel(
    const unsigned short* __restrict__ A, const unsigned short* __restrict__ Wsw,
    const float* __restrict__ bias, void* __restrict__ Y,
    int K, int N, int relu, int out_f32) {
  const int t = threadIdx.x;
  const int lane = t & 63;
  const int w = t >> 6;
  const int ln = lane & 15, q = lane >> 4;
  const int wm = w >> 1, wn = w & 1;
  const int n0 = blockIdx.x * 128;
  const int mblk = blockIdx.y;
  const int s = mblk >> 6;                  // 4096/64 = 64 m-blocks per source
  const int m0 = mblk * 64;
  const int nb = N >> 7, kb = K >> 6;

  const unsigned short* Ag = A + (size_t)m0 * K;
  const unsigned short* Bt = Wsw + ((size_t)(s * nb + blockIdx.x) * kb) * 8192;
  const float* bs = bias + (size_t)s * N;

  __shared__ unsigned short Asm[2 * 64 * 32];     // 8 KB (two 32-k halves)
  __shared__ unsigned short Bsm[2 * 8192];        // 32 KB double buffer

  const int arow0 = t >> 3, ak8 = t & 7;
  const int aL0 = (ak8 >> 2) * 2048 + arow0 * 32 + (ak8 & 3) * 8;
  const size_t gA0 = (size_t)arow0 * K + ak8 * 8;

  // preload A regs (tile 0) + issue async B tile 0
  bf16x8 ra0 = *(const bf16x8*)(Ag + gA0);
  bf16x8 ra1 = *(const bf16x8*)(Ag + gA0 + (size_t)32 * K);
#pragma unroll
  for (int p = 0; p < 4; p++)
    gl2lds16(Bt + (size_t)(p * 256 + t) * 8, &Bsm[(size_t)(p * 256 + t) * 8]);

  f32x4 acc[2][4];
#pragma unroll
  for (int i = 0; i < 2; i++)
#pragma unroll
    for (int j = 0; j < 4; j++) acc[i][j] = (f32x4){0.f, 0.f, 0.f, 0.f};

  for (int kt = 0; kt < kb; kt++) {
    *(bf16x8*)&Asm[aL0] = ra0;
    *(bf16x8*)&Asm[aL0 + 1024] = ra1;
    __syncthreads();                       // drains vmcnt: B tile kt complete
    const unsigned short* Bcur = &Bsm[(kt & 1) * 8192];
    if (kt + 1 < kb) {
      const unsigned short* Bn = Bt + (size_t)(kt + 1) * 8192;
      unsigned short* Bd = &Bsm[((kt + 1) & 1) * 8192];
#pragma unroll
      for (int p = 0; p < 4; p++)
        gl2lds16(Bn + (size_t)(p * 256 + t) * 8, Bd + (size_t)(p * 256 + t) * 8);
      const size_t g = gA0 + (size_t)(kt + 1) * 64;
      ra0 = *(const bf16x8*)(Ag + g);
      ra1 = *(const bf16x8*)(Ag + g + (size_t)32 * K);
    }
    bf16x8 af[2][2], bf[4][2];
#pragma unroll
    for (int ti = 0; ti < 2; ti++)
#pragma unroll
      for (int ksl = 0; ksl < 2; ksl++)
        af[ti][ksl] = *(const bf16x8*)&Asm[ksl * 2048 + (wm * 32 + ti * 16 + ln) * 32 + q * 8];
#pragma unroll
    for (int tj = 0; tj < 4; tj++)
#pragma unroll
      for (int ksl = 0; ksl < 2; ksl++)
        bf[tj][ksl] = *(const bf16x8*)&Bcur[ksl * 4096 + (wn * 64 + tj * 16 + ln) * 32 + q * 8];
#pragma unroll
    for (int ksl = 0; ksl < 2; ksl++)
#pragma unroll
      for (int ti = 0; ti < 2; ti++)
#pragma unroll
        for (int tj = 0; tj < 4; tj++)
          acc[ti][tj] = __builtin_amdgcn_mfma_f32_16x16x32_bf16(af[ti][ksl], bf[tj][ksl], acc[ti][tj], 0, 0, 0);
    __syncthreads();
  }

#pragma unroll
  for (int ti = 0; ti < 2; ti++)
#pragma unroll
    for (int tj = 0; tj < 4; tj++) {
      const int cc = n0 + wn * 64 + tj * 16 + ln;
      const float bv = bs[cc];
#pragma unroll
      for (int reg = 0; reg < 4; reg++) {
        const int r = m0 + wm * 32 + ti * 16 + q * 4 + reg;
        float v = acc[ti][tj][reg] + bv;
        if (relu) v = fmaxf(v, 0.0f);
        if (out_f32) ((float*)Y)[(size_t)r * N + cc] = v;
        else ((unsigned short*)Y)[(size_t)r * N + cc] = f2bf(v);
      }
    }
}

// ---------------- fused attention score + softmax + fuse (4 b per block) --------
__global__ __launch_bounds__(256) void score_fuse_kernel(
    const float* __restrict__ emb, const float* __restrict__ qw1,
    const float* __restrict__ qb1, const float* __restrict__ qw2,
    float* __restrict__ fused) {
  const int b0 = blockIdx.x * 4;
  const int t = threadIdx.x;
  const int g = t >> 7, d = t & 127;
  __shared__ float e[12][D_];
  __shared__ float red[4][6];
  __shared__ float sc[12];
#pragma unroll
  for (int i = 0; i < 3; i++) {
    int idx = i * 512 + t * 2;
    int r = idx >> 7, dd = idx & 127;
    int s = r >> 2, bi = r & 3;
    *(float2*)&e[r][dd] = *(const float2*)(emb + ((size_t)(s * B_ + b0 + bi)) * D_ + dd);
  }
  __syncthreads();
  float acc[6] = {0.f, 0.f, 0.f, 0.f, 0.f, 0.f};
  for (int i = 0; i < D_; i++) {
    float w = qw1[i * D_ + d];
#pragma unroll
    for (int j = 0; j < 6; j++) acc[j] = fmaf(e[g * 6 + j][i], w, acc[j]);
  }
  const float qb = qb1[d], q2 = qw2[d];
  float val[6];
#pragma unroll
  for (int j = 0; j < 6; j++) val[j] = tanhf(acc[j] + qb) * q2;
  const int wave = t >> 6;
#pragma unroll
  for (int j = 0; j < 6; j++) {
    float v = waveReduceSum(val[j]);
    if ((t & 63) == 0) red[wave][j] = v;
  }
  __syncthreads();
  if (t < 12) {
    int gg = t / 6, j = t % 6;
    sc[gg * 6 + j] = red[2 * gg][j] + red[2 * gg + 1][j];
  }
  __syncthreads();
#pragma unroll
  for (int p = 0; p < 2; p++) {
    int idx = p * 256 + t;
    int bi = idx >> 7, dd = idx & 127;
    float s0 = sc[bi], s1 = sc[4 + bi], s2 = sc[8 + bi];
    float mx = fmaxf(s0, fmaxf(s1, s2));
    float e0 = __expf(s0 - mx), e1 = __expf(s1 - mx), e2 = __expf(s2 - mx);
    float inv = 1.0f / (e0 + e1 + e2);
    fused[(size_t)(b0 + bi) * D_ + dd] =
        (e0 * e[bi][dd] + e1 * e[4 + bi][dd] + e2 * e[8 + bi][dd]) * inv;
  }
}

// ---------------- fused codebook norms + bf16 convert + column-sum partials -----
__global__ __launch_bounds__(512) void cbns_kernel(const float* __restrict__ cb,
                                                   float* __restrict__ cbn2,
                                                   float* __restrict__ cbsumP,
                                                   unsigned short* __restrict__ cbb) {
  const int m = blockIdx.x >> 3;
  const int k0 = (blockIdx.x & 7) * 64;
  const int t = threadIdx.x, w = t >> 6, lane = t & 63;
  __shared__ float invn[64];
#pragma unroll
  for (int r = w * 8; r < w * 8 + 8; r++) {
    int k = k0 + r;
    float2 v = *(const float2*)(cb + ((size_t)m * K_ + k) * D_ + lane * 2);
    unsigned short* crow = cbb + ((size_t)m * K_ + k) * D_;
    crow[lane * 2 + 0] = f2bf(v.x);
    crow[lane * 2 + 1] = f2bf(v.y);
    float n2 = waveXorSum(v.x * v.x + v.y * v.y);
    if (lane == 0) {
      cbn2[m * K_ + k] = n2;
      invn[r] = 1.0f / fmaxf(sqrtf(n2), EPS_);
    }
  }
  __syncthreads();
  if (t < D_) {
    float acc = 0.0f;
    for (int r = 0; r < 64; r++)
      acc += cb[((size_t)m * K_ + k0 + r) * D_ + t] * invn[r];
    cbsumP[(size_t)blockIdx.x * D_ + t] = acc;
  }
}

// ---------------- residual VQ: MFMA distance GEMM ----------------
__global__ __launch_bounds__(512) void vq_mfma_kernel(
    const float* __restrict__ fused, const float* __restrict__ cb,
    const unsigned short* __restrict__ cbb, const float* __restrict__ cbn2,
    float* __restrict__ qsum) {
  const int r0 = blockIdx.x * 16;
  const int t = threadIdx.x;
  const int w = t >> 6, lane = t & 63;
  const int ln = lane & 15, q = lane >> 4;
  __shared__ float resv[16][D_];
  __shared__ unsigned short resb[16][D_];
  __shared__ float candd[8][16];
  __shared__ int candk[8][16];
  __shared__ int bestk[16];

  {
    int idx = t * 4;
    int r = idx >> 7, dd = idx & 127;
    float4 v = *(const float4*)(fused + (size_t)(r0 + r) * D_ + dd);
    *(float4*)&resv[r][dd] = v;
    resb[r][dd + 0] = f2bf(v.x); resb[r][dd + 1] = f2bf(v.y);
    resb[r][dd + 2] = f2bf(v.z); resb[r][dd + 3] = f2bf(v.w);
  }
  __syncthreads();

  for (int c = 0; c < C_; c++) {
    bf16x8 a[4];
#pragma unroll
    for (int ks = 0; ks < 4; ks++)
      a[ks] = *(const bf16x8*)&resb[ln][ks * 32 + q * 8];
    f32x4 acc[4];
#pragma unroll
    for (int tt = 0; tt < 4; tt++) acc[tt] = (f32x4){0.f, 0.f, 0.f, 0.f};
#pragma unroll
    for (int tt = 0; tt < 4; tt++) {
      const int n = w * 64 + tt * 16 + ln;
      const unsigned short* bp = cbb + ((size_t)c * K_ + n) * D_;
#pragma unroll
      for (int ks = 0; ks < 4; ks++) {
        bf16x8 b = *(const bf16x8*)(bp + ks * 32 + q * 8);
        acc[tt] = __builtin_amdgcn_mfma_f32_16x16x32_bf16(a[ks], b, acc[tt], 0, 0, 0);
      }
    }
    float bd[4]; int bk[4];
#pragma unroll
    for (int reg = 0; reg < 4; reg++) { bd[reg] = 3.4e38f; bk[reg] = 0x7fffffff; }
#pragma unroll
    for (int tt = 0; tt < 4; tt++) {
      const int col = w * 64 + tt * 16 + ln;
      const float n2 = cbn2[c * K_ + col];
#pragma unroll
      for (int reg = 0; reg < 4; reg++) {
        float dist = n2 - 2.0f * acc[tt][reg];
        if (dist < bd[reg] || (dist == bd[reg] && col < bk[reg])) { bd[reg] = dist; bk[reg] = col; }
      }
    }
#pragma unroll
    for (int reg = 0; reg < 4; reg++) {
#pragma unroll
      for (int off = 8; off > 0; off >>= 1) {
        float d1 = __shfl_down(bd[reg], off, 16);
        int k1 = __shfl_down(bk[reg], off, 16);
        if (d1 < bd[reg] || (d1 == bd[reg] && k1 < bk[reg])) { bd[reg] = d1; bk[reg] = k1; }
      }
      if (ln == 0) { candd[w][q * 4 + reg] = bd[reg]; candk[w][q * 4 + reg] = bk[reg]; }
    }
    __syncthreads();
    if (w == 0) {
      int row = lane >> 2, g = lane & 3;
      float d0 = candd[2 * g][row]; int k0 = candk[2 * g][row];
      float d1 = candd[2 * g + 1][row]; int k1 = candk[2 * g + 1][row];
      if (d1 < d0 || (d1 == d0 && k1 < k0)) { d0 = d1; k0 = k1; }
#pragma unroll
      for (int off = 2; off > 0; off >>= 1) {
        float dn = __shfl_down(d0, off, 4);
        int kn = __shfl_down(k0, off, 4);
        if (dn < d0 || (dn == d0 && kn < k0)) { d0 = dn; k0 = kn; }
      }
      if (g == 0) bestk[row] = k0;
    }
    __syncthreads();
    {
      int idx = t * 4;
      int r = idx >> 7, dd = idx & 127;
      const float4 qv = *(const float4*)(cb + ((size_t)c * K_ + bestk[r]) * D_ + dd);
      float4 rv = *(float4*)&resv[r][dd];
      rv.x -= qv.x; rv.y -= qv.y; rv.z -= qv.z; rv.w -= qv.w;
      *(float4*)&resv[r][dd] = rv;
      resb[r][dd + 0] = f2bf(rv.x); resb[r][dd + 1] = f2bf(rv.y);
      resb[r][dd + 2] = f2bf(rv.z); resb[r][dd + 3] = f2bf(rv.w);
    }
    __syncthreads();
  }

  {
    int idx = t * 4;
    int r = idx >> 7, dd = idx & 127;
    float4 f = *(const float4*)(fused + (size_t)(r0 + r) * D_ + dd);
    float4 rv = *(float4*)&resv[r][dd];
    f.x -= rv.x; f.y -= rv.y; f.z -= rv.z; f.w -= rv.w;
    *(float4*)(qsum + (size_t)(r0 + r) * D_ + dd) = f;
  }
}

// ---------------- fused normalize + pos: block per b, wave per row ----------------
__global__ __launch_bounds__(256) void normpos_kernel(
    const float* __restrict__ qsum, const float* __restrict__ emb,
    unsigned short* __restrict__ zb, float* __restrict__ pos) {
  const int b = blockIdx.x;
  const int w = threadIdx.x >> 6, lane = threadIdx.x & 63;
  __shared__ float zl[4][D_];
  const float* src = (w == 0) ? (qsum + (size_t)b * D_)
                              : (emb + (size_t)((w - 1) * B_ + b) * D_);
  float2 v = *(const float2*)(src + lane * 2);
  float n2 = waveXorSum(v.x * v.x + v.y * v.y);
  float inv = 1.0f / fmaxf(sqrtf(n2), EPS_);
  float zx = v.x * inv, zy = v.y * inv;
  const size_t g = (size_t)w * B_ + b;
  zb[g * D_ + lane * 2 + 0] = f2bf(zx);
  zb[g * D_ + lane * 2 + 1] = f2bf(zy);
  zl[w][lane * 2] = zx; zl[w][lane * 2 + 1] = zy;
  __syncthreads();
  if (w >= 1) {
    float2 a = *(const float2*)&zl[0][lane * 2];
    float dsum = waveXorSum(a.x * zx + a.y * zy);
    if (lane == 0) pos[(w - 1) * B_ + b] = dsum;
  }
}

// ---------------- contrastive exp-rowsums: LDS-staged B tiles ----------------
__global__ __launch_bounds__(256) void contrast_mfma_kernel(
    const unsigned short* __restrict__ zb, float* __restrict__ rsP) {
  const int jc = blockIdx.x, ib = blockIdx.y, m = blockIdx.z;
  const int t = threadIdx.x;
  const int w = t >> 6, lane = t & 63;
  const int ln = lane & 15, q = lane >> 4;
  const int i0 = ib * 128 + w * 32;
  const unsigned short* Za = zb;
  const unsigned short* Zm = zb + (size_t)m * B_ * D_;

  __shared__ unsigned short Zsm[64 * 136];

  bf16x8 a[2][4];
#pragma unroll
  for (int si = 0; si < 2; si++)
#pragma unroll
    for (int ks = 0; ks < 4; ks++)
      a[si][ks] = *(const bf16x8*)(Za + (size_t)(i0 + si * 16 + ln) * D_ + ks * 32 + q * 8);

  const unsigned short* tb = Zm + (size_t)(jc * 1024) * D_;
  bf16x8 rz[4];
#pragma unroll
  for (int p = 0; p < 4; p++)
    rz[p] = *(const bf16x8*)(tb + t * 8 + p * 2048);

  float e[2][4] = {};
  for (int jt = 0; jt < 16; jt++) {
#pragma unroll
    for (int p = 0; p < 4; p++) {
      int c = t + p * 256;
      *(bf16x8*)&Zsm[(c >> 4) * 136 + (c & 15) * 8] = rz[p];
    }
    __syncthreads();
    if (jt + 1 < 16) {
      const unsigned short* tn = Zm + (size_t)(jc * 1024 + (jt + 1) * 64) * D_;
#pragma unroll
      for (int p = 0; p < 4; p++)
        rz[p] = *(const bf16x8*)(tn + t * 8 + p * 2048);
    }
    f32x4 acc[2][4];
#pragma unroll
    for (int si = 0; si < 2; si++)
#pragma unroll
      for (int tj = 0; tj < 4; tj++) acc[si][tj] = (f32x4){0.f, 0.f, 0.f, 0.f};
#pragma unroll
    for (int tj = 0; tj < 4; tj++) {
      bf16x8 b[4];
#pragma unroll
      for (int ks = 0; ks < 4; ks++)
        b[ks] = *(const bf16x8*)&Zsm[(tj * 16 + ln) * 136 + ks * 32 + q * 8];
#pragma unroll
      for (int ks = 0; ks < 4; ks++) {
        acc[0][tj] = __builtin_amdgcn_mfma_f32_16x16x32_bf16(a[0][ks], b[ks], acc[0][tj], 0, 0, 0);
        acc[1][tj] = __builtin_amdgcn_mfma_f32_16x16x32_bf16(a[1][ks], b[ks], acc[1][tj], 0, 0, 0);
      }
    }
#pragma unroll
    for (int si = 0; si < 2; si++)
#pragma unroll
      for (int reg = 0; reg < 4; reg++) {
        float s = 0.f;
#pragma unroll
        for (int tj = 0; tj < 4; tj++) s += __expf(acc[si][tj][reg] * INV_T);
        e[si][reg] += s;
      }
    __syncthreads();
  }
#pragma unroll
  for (int si = 0; si < 2; si++)
#pragma unroll
    for (int reg = 0; reg < 4; reg++) {
#pragma unroll
      for (int off = 8; off > 0; off >>= 1)
        e[si][reg] += __shfl_xor(e[si][reg], off, 16);
    }
  if (ln == 0) {
#pragma unroll
    for (int si = 0; si < 2; si++)
#pragma unroll
      for (int reg = 0; reg < 4; reg++)
        rsP[((size_t)m * 4 + jc) * B_ + i0 + si * 16 + q * 4 + reg] = e[si][reg];
  }
}

// ---------------- fused loss reduce + finalize (4 blocks) ----------------
__global__ __launch_bounds__(256) void final2_kernel(const float* __restrict__ rsP,
                                                     const float* __restrict__ pos,
                                                     const float* __restrict__ cbsumP,
                                                     float* __restrict__ out) {
  const int blk = blockIdx.x;
  const int t = threadIdx.x;
  __shared__ float red[4];
  if (blk == 0) {
    float acc = 0.0f;
    if (t < D_) {
#pragma unroll
      for (int m = 0; m < C_; m++) {
        float v = 0.0f;
#pragma unroll
        for (int b8 = 0; b8 < 8; b8++) v += cbsumP[(size_t)(m * 8 + b8) * D_ + t];
        acc += v * v;
      }
    }
    float v = waveReduceSum(acc);
    if ((t & 63) == 0) red[t >> 6] = v;
    __syncthreads();
    if (t == 0) {
      out[0] = (red[0] + red[1] + red[2] + red[3]) * (1.0f / (3.0f * 512.0f * 512.0f));
      out[1] = 0.0f;
    }
  } else {
    const int s = blk - 1;
    float acc = 0.0f;
    for (int it = 0; it < 16; it++) {
      const int i = it * 256 + t;
      float denom = -EXP10;
#pragma unroll
      for (int jc = 0; jc < 4; jc++) {
        denom += rsP[(size_t)jc * B_ + i];
        denom += rsP[((size_t)(1 + s) * 4 + jc) * B_ + i];
      }
      acc += logf(denom) - pos[s * B_ + i] * INV_T;
    }
    float v = waveReduceSum(acc);
    if ((t & 63) == 0) red[t >> 6] = v;
    __syncthreads();
    if (t == 0)
      out[2 + s] = (red[0] + red[1] + red[2] + red[3]) * (1.0f / 4096.0f);
  }
}

extern "C" void kernel_launch(void* const* d_in, const int* in_sizes, int n_in,
                              void* d_out, int out_size, void* d_ws, size_t ws_size,
                              hipStream_t stream) {
  const float* x    = (const float*)d_in[0];
  const float* w1   = (const float*)d_in[1];
  const float* b1   = (const float*)d_in[2];
  const float* w2   = (const float*)d_in[3];
  const float* b2   = (const float*)d_in[4];
  const float* w3   = (const float*)d_in[5];
  const float* b3   = (const float*)d_in[6];
  const float* w4   = (const float*)d_in[7];
  const float* b4   = (const float*)d_in[8];
  const float* qw1  = (const float*)d_in[9];
  const float* qb1  = (const float*)d_in[10];
  const float* qw2  = (const float*)d_in[11];
  const float* cb   = (const float*)d_in[12];
  float* out = (float*)d_out;
  char* base = (char*)d_ws;

  size_t o = 0;
  auto alloc = [&](size_t bytes) { size_t r = o; o += (bytes + 255) & ~(size_t)255; return r; };
  size_t o_xb   = alloc((size_t)S_ * B_ * DIN_ * 2);
  size_t o_wt1  = alloc((size_t)S_ * H1_ * DIN_ * 2);
  size_t o_wt2  = alloc((size_t)S_ * H2_ * H1_ * 2);
  size_t o_wt3  = alloc((size_t)S_ * H3_ * H2_ * 2);
  size_t o_wt4  = alloc((size_t)S_ * D_ * H3_ * 2);
  size_t o_h1b  = alloc((size_t)S_ * B_ * H1_ * 2);
  size_t o_h2b  = alloc((size_t)S_ * B_ * H2_ * 2);
  size_t o_h3b  = alloc((size_t)S_ * B_ * H3_ * 2);
  size_t o_emb  = alloc((size_t)S_ * B_ * D_ * 4);
  size_t o_fus  = alloc((size_t)B_ * D_ * 4);
  size_t o_qs   = alloc((size_t)B_ * D_ * 4);
  size_t o_zb   = alloc((size_t)4 * B_ * D_ * 2);
  size_t o_cbn2 = alloc((size_t)C_ * K_ * 4);
  size_t o_cbb  = alloc((size_t)C_ * K_ * D_ * 2);
  size_t o_rsP  = alloc((size_t)4 * 4 * B_ * 4);
  size_t o_cbsP = alloc((size_t)C_ * 8 * D_ * 4);
  size_t o_pos  = alloc((size_t)S_ * B_ * 4);
  (void)ws_size; (void)in_sizes; (void)n_in; (void)out_size;

  unsigned short* xb  = (unsigned short*)(base + o_xb);
  unsigned short* wt1 = (unsigned short*)(base + o_wt1);
  unsigned short* wt2 = (unsigned short*)(base + o_wt2);
  unsigned short* wt3 = (unsigned short*)(base + o_wt3);
  unsigned short* wt4 = (unsigned short*)(base + o_wt4);
  unsigned short* h1b = (unsigned short*)(base + o_h1b);
  unsigned short* h2b = (unsigned short*)(base + o_h2b);
  unsigned short* h3b = (unsigned short*)(base + o_h3b);
  float* emb   = (float*)(base + o_emb);
  float* fused = (float*)(base + o_fus);
  float* qsum  = (float*)(base + o_qs);
  unsigned short* zb = (unsigned short*)(base + o_zb);
  float* cbn2  = (float*)(base + o_cbn2);
  unsigned short* cbb = (unsigned short*)(base + o_cbb);
  float* rsP   = (float*)(base + o_rsP);
  float* cbsumP= (float*)(base + o_cbsP);
  float* pos   = (float*)(base + o_pos);

  // fused prep: x->bf16 + all weight transposes (one launch)
  const int prep_blocks = (S_ * B_ * DIN_) / 1024 + 1536 + 576 + 288 + 96;
  prep_kernel<<<dim3(prep_blocks), 256, 0, stream>>>(x, xb, w1, wt1, w2, wt2, w3, wt3, w4, wt4);

  // codebook norms + bf16 codebook + cbsum partials
  cbns_kernel<<<dim3(C_ * 8), 512, 0, stream>>>(cb, cbn2, cbsumP, cbb);

  // encoder MLP via LDS-staged MFMA (BK=64, async B staging)
  const int Mtot = S_ * B_;
  gemm_lds_kernel<<<dim3(H1_ / 128, Mtot / 64), 256, 0, stream>>>(xb, wt1, b1, h1b, DIN_, H1_, 1, 0);
  gemm_lds_kernel<<<dim3(H2_ / 128, Mtot / 64), 256, 0, stream>>>(h1b, wt2, b2, h2b, H1_, H2_, 1, 0);
  gemm_lds_kernel<<<dim3(H3_ / 128, Mtot / 64), 256, 0, stream>>>(h2b, wt3, b3, h3b, H2_, H3_, 1, 0);
  gemm_lds_kernel<<<dim3(D_ / 128, Mtot / 64), 256, 0, stream>>>(h3b, wt4, b4, emb, H3_, D_, 0, 1);

  // fused attention score + softmax + fuse
  score_fuse_kernel<<<dim3(B_ / 4), 256, 0, stream>>>(emb, qw1, qb1, qw2, fused);

  // residual VQ (MFMA distance GEMM)
  vq_mfma_kernel<<<dim3(B_ / 16), 512, 0, stream>>>(fused, cb, cbb, cbn2, qsum);

  // fused normalize + pos
  normpos_kernel<<<dim3(B_), 256, 0, stream>>>(qsum, emb, zb, pos);

  // contrastive rowsum partials
  contrast_mfma_kernel<<<dim3(4, 32, 4), 256, 0, stream>>>(zb, rsP);

  // fused loss reduce + finalize
  final2_kernel<<<dim3(4), 256, 0, stream>>>(rsP, pos, cbsumP, out);
}